// Round 1
// baseline (473.237 us; speedup 1.0000x reference)
//
#include <hip/hip_runtime.h>
#include <hip/hip_fp16.h>

// LSTM_48850958024796 — R17: split scan kernels into 512-thread blocks,
// 2 independent barrier domains per CU to overlap the per-step serial chain
// (ds_read -> MFMA x4 -> swizzle -> exp-chain -> f2bf -> ds_write -> barrier).
// R16 counters: lstm_l0 134us, MfmaUtil 16.5%, per-SIMD VALU issue ~17%
// -> latency-bound with a single 1024-thr barrier group per CU.
// l0: MB=4, dense 4 tiles/wave on waves 0..6 (l1's proven structure),
//     grid (256,2)=512 blocks = 2/CU; wave 7 prefetches x.
// l1: MB1=2, grid 512 blocks = 2/CU, partner2 spread (swizzle 0x11),
//     duplicate lanes l16>=8 masked on LDS write; deletes 9 idle waves.
// Falsified levers (do not retry): barrier_nv (neutral), unroll-2 (neg),
// mega-kernel+grid.sync (724), wave specialization in one kernel (spill, 877).
// Scan math (R3-proven): gates^T = W(A) @ [h|x|1]^T(B), cols gate-interleaved
// (n'=4j+gate).

typedef __attribute__((ext_vector_type(8))) short bf16x8;
typedef __attribute__((ext_vector_type(4))) float f32x4;

constexpr int Bsz = 1024, Tt = 128, IN_ = 5, H = 100, G = 400, D1 = 200;
constexpr int NP = 512;   // packed gate cols (32 tiles of 16)
constexpr int NT = 25;    // real tiles (400/16)
constexpr int MB = 4;     // batch rows per block (l0)
constexpr int MB1 = 2;    // batch rows per block (l1)

__device__ __forceinline__ float sigm(float x)   { return 1.f / (1.f + __expf(-x)); }
__device__ __forceinline__ float tanhf_(float x) { return 1.f - 2.f / (__expf(2.f * x) + 1.f); }
__device__ __forceinline__ unsigned short f2bf(float f) {
  unsigned u = __float_as_uint(f);
  u += 0x7fff + ((u >> 16) & 1);
  return (unsigned short)(u >> 16);
}
// src lane = lane & ~12 (keeps bits 0,1 and 4): MB=4, 4-tile spread
__device__ __forceinline__ float partner4(float v) {
  return __uint_as_float(
      (unsigned)__builtin_amdgcn_ds_swizzle((int)__float_as_uint(v), 0x13));
}
// src lane = lane & ~14 (keeps bits 0 and 4): MB1=2, 4-tile spread + dup mask
__device__ __forceinline__ float partner2(float v) {
  return __uint_as_float(
      (unsigned)__builtin_amdgcn_ds_swizzle((int)__float_as_uint(v), 0x11));
}

// packed col n' (0..511): j=n'>>2, gate=n'&3, src row n = gate*100+j; j>=100->0
__device__ __forceinline__ void pack_body(
    const float* wA, int KA, const float* wB, int KB, int kbo,
    const float* b1, const float* b2, int bias_k,
    unsigned short* dst, int Kg, int idx) {
  if (idx >= Kg * NP * 8) return;
  int jj = idx & 7, rest = idx >> 3;
  int np_ = rest % NP, g = rest / NP;
  int j = np_ >> 2, gate = np_ & 3;
  int k = g * 8 + jj;
  float v = 0.f;
  if (j < H) {
    int n = gate * H + j;
    if (k < KA) v = wA[n * KA + k];
    else if (KB > 0 && k >= kbo && k < kbo + KB) v = wB[n * KB + (k - kbo)];
    else if (k == bias_k) v = b1[n] + b2[n];
  }
  dst[idx] = f2bf(v);
}

__global__ void pack_all(
    const float* __restrict__ w_hh_l0f, const float* __restrict__ w_ih_l0f,
    const float* __restrict__ b_ih_l0f, const float* __restrict__ b_hh_l0f,
    const float* __restrict__ w_hh_l0b, const float* __restrict__ w_ih_l0b,
    const float* __restrict__ b_ih_l0b, const float* __restrict__ b_hh_l0b,
    const float* __restrict__ w_hh_l1f, const float* __restrict__ b_ih_l1f,
    const float* __restrict__ b_hh_l1f,
    const float* __restrict__ w_ih_l1f, const float* __restrict__ w_ih_l1b,
    const float* __restrict__ b_ih_l1b, const float* __restrict__ b_hh_l1b,
    unsigned short* __restrict__ pk0f, unsigned short* __restrict__ pk0b,
    unsigned short* __restrict__ pkhh, unsigned short* __restrict__ pkxg,
    unsigned short* __restrict__ pk1b) {
  int idx = blockIdx.x * 256 + threadIdx.x;
  switch (blockIdx.y) {
    case 0: pack_body(w_hh_l0f, 100, w_ih_l0f, 5, 100, b_ih_l0f, b_hh_l0f, 105, pk0f, 16, idx); break;
    case 1: pack_body(w_hh_l0b, 100, w_ih_l0b, 5, 100, b_ih_l0b, b_hh_l0b, 105, pk0b, 16, idx); break;
    case 2: pack_body(w_hh_l1f, 100, nullptr, 0, 0, b_ih_l1f, b_hh_l1f, -1, pkhh, 16, idx); break;
    case 3: pack_body(w_ih_l1f, 200, nullptr, 0, 0, b_ih_l1f, b_hh_l1f, 200, pkxg, 28, idx); break;
    default: pack_body(w_ih_l1b, 200, nullptr, 0, 0, b_ih_l1b, b_hh_l1b, 200, pk1b, 28, idx);
  }
}

// ------------- layer 0 scan (grid = 256 x 2 dirs, 512 thr, 2 blocks/CU) ----
__global__ __launch_bounds__(512, 4) void lstm_l0(
    const float* __restrict__ x,
    const unsigned short* __restrict__ pk_f, const unsigned short* __restrict__ pk_b,
    unsigned short* __restrict__ h0fT, unsigned short* __restrict__ h0bT) {
  __shared__ __align__(16) short A_s[2][16][16][8];  // [buf][kg][m16][jj], K=128

  const int tid = threadIdx.x;
  const int lane = tid & 63, w = tid >> 6;       // 8 waves
  const int q = lane >> 4, l16 = lane & 15;
  const int b0 = blockIdx.x * MB;
  const int dir = blockIdx.y;
  const unsigned short* pk = dir ? pk_b : pk_f;
  unsigned short* hT = dir ? h0bT : h0fT;

  for (int i = tid; i < 2 * 16 * 16 * 8; i += 512) ((short*)A_s)[i] = 0;

  const bool busy = (w < 7);                 // waves 0..6 own tiles 4w..4w+3
  const int m = l16 & 3, g16 = l16 >> 2;
  const int myMt = w * 4 + g16;
  const int jme = myMt * 4 + q;              // my element's j (>=100 invalid)
  const bool evalid = busy && (myMt < NT);
  bool tv[4];
  bf16x8 wf[4][4];
  if (busy) {
#pragma unroll
    for (int i = 0; i < 4; ++i) {
      int mt = w * 4 + i; tv[i] = (mt < NT);
#pragma unroll
      for (int kt = 0; kt < 4; ++kt)
        wf[i][kt] = *(const bf16x8*)(pk + ((size_t)(kt * 4 + q) * NP + mt * 16 + l16) * 8);
    }
  }
  float c = 0.f;
  // x prefetch on wave 7 (non-busy): xt in [0, 20)
  const int xt = tid - 448;
  const bool xl = (xt >= 0 && xt < MB * IN_);
  const int xm = xl ? xt / IN_ : 0;
  const int xe = xl ? xt - xm * IN_ : 0;
  const int sm = tid / 25, sj = (tid - (tid / 25) * 25) * 4;  // h store (tid<100)
  const float* xp = x + ((size_t)(b0 + xm) * Tt + (dir ? Tt - 2 : 1)) * IN_ + xe;
  const int xstride = dir ? -IN_ : IN_;
  unsigned short* hp =
      hT + ((size_t)(dir ? Tt - 1 : 0) * Bsz + b0 + sm) * H + sj;
  const int hstride = dir ? -(Bsz * H) : (Bsz * H);
  __syncthreads();
  if (tid < 16) {  // bias-one col k=105 (kg13,jj1), both bufs
    A_s[0][13][tid][1] = (short)f2bf(1.f);
    A_s[1][13][tid][1] = (short)f2bf(1.f);
  }
  if (tid < MB * IN_) {  // x(t_first) -> buf0, direct f32 read
    int t0 = dir ? (Tt - 1) : 0;
    int m0 = tid / IN_, e0 = tid - m0 * IN_;
    int k = 100 + e0;
    A_s[0][k >> 3][m0][k & 7] =
        (short)f2bf(x[((size_t)(b0 + m0) * Tt + t0) * IN_ + e0]);
  }
  __syncthreads();

  int p = 0;
  for (int step = 0; step < Tt; ++step) {
    if (step > 0 && tid < 100) {  // coalesced store of h(prev) from buf p
      *(uint2*)hp = *(const uint2*)&A_s[p][sj >> 3][sm][sj & 7];
      hp += hstride;
    }
    float xn = 0.f;
    const bool do_x = xl && (step < Tt - 1);
    if (do_x) { xn = *xp; xp += xstride; }
    if (busy) {
      bf16x8 hfrag[4];
#pragma unroll
      for (int kt = 0; kt < 4; ++kt) hfrag[kt] = *(const bf16x8*)A_s[p][kt * 4 + q][l16];
      f32x4 acc[4];
#pragma unroll
      for (int i = 0; i < 4; ++i) {
        acc[i] = (f32x4){0.f, 0.f, 0.f, 0.f};
        if (!tv[i]) continue;
#pragma unroll
        for (int kt = 0; kt < 4; ++kt)
          acc[i] = __builtin_amdgcn_mfma_f32_16x16x32_bf16(wf[i][kt], hfrag[kt], acc[i], 0, 0, 0);
      }
      float gr[4];
#pragma unroll
      for (int r = 0; r < 4; ++r) {
        float v0 = partner4(acc[0][r]);
        float v1 = partner4(acc[1][r]);
        float v2 = partner4(acc[2][r]);
        float v3 = partner4(acc[3][r]);
        float lo = (g16 & 1) ? v1 : v0;
        float hi = (g16 & 1) ? v3 : v2;
        gr[r] = (g16 & 2) ? hi : lo;
      }
      float cc = sigm(gr[1]) * c + sigm(gr[0]) * tanhf_(gr[2]);
      c = cc;
      float h = sigm(gr[3]) * tanhf_(cc);
      if (evalid) A_s[1 - p][jme >> 3][m][jme & 7] = (short)f2bf(h);
    }
    if (do_x) {
      int k = 100 + xe;
      A_s[1 - p][k >> 3][xm][k & 7] = (short)f2bf(xn);
    }
    __syncthreads();
    p ^= 1;
  }
  if (tid < 100) *(uint2*)hp = *(const uint2*)&A_s[p][sj >> 3][sm][sj & 7];  // final h
}

// ---- xgT[t*1024+b][400] = [h0f|h0b] @ W_ih_l1f^T + bias (fp16, interleaved) --
__global__ __launch_bounds__(1024, 1) void gemm_xg(
    const unsigned short* __restrict__ h0fT, const unsigned short* __restrict__ h0bT,
    const unsigned short* __restrict__ pkw, __half* __restrict__ xg) {
  __shared__ __align__(16) short B_s[28][64][8];  // K=224 aug (k=200 bias-one)
  const int tid = threadIdx.x;
  const int lane = tid & 63, w = tid >> 6;   // 16 waves
  const int q = lane >> 4, l16 = lane & 15;
  const int r0 = blockIdx.x * 64;            // rows r = t*1024+b
  const size_t base = (size_t)r0 * H;

  for (int i = tid; i < 3 * 64 * 8; i += 1024) {  // kg 25..27: zero + bias-one
    int jj = i & 7, gl = i >> 9;
    ((short*)&B_s[25][0][0])[i] = (short)((gl == 0 && jj == 0) ? f2bf(1.f) : 0);
  }
  for (int idx = tid; idx < 1600; idx += 1024) {  // h0f k=0..99, h0b k=100..199
    int m = idx / 25, j0 = (idx - (idx / 25) * 25) * 4;
    *(uint2*)&B_s[j0 >> 3][m][j0 & 7] = *(const uint2*)(h0fT + base + m * H + j0);
    int k = 100 + j0;
    *(uint2*)&B_s[k >> 3][m][k & 7] = *(const uint2*)(h0bT + base + m * H + j0);
  }

  const int mtA = w, mtB = w + 16;
  const bool bvalid = (mtB < NT);
  bf16x8 wfA[7], wfB[7];
#pragma unroll
  for (int kt = 0; kt < 7; ++kt) {
    wfA[kt] = *(const bf16x8*)(pkw + ((size_t)(kt * 4 + q) * NP + mtA * 16 + l16) * 8);
    wfB[kt] = *(const bf16x8*)(pkw + ((size_t)(kt * 4 + q) * NP + mtB * 16 + l16) * 8);
  }
  const int jA = mtA * 4 + q, jB = mtB * 4 + q;
  __syncthreads();

#pragma unroll
  for (int rg = 0; rg < 4; ++rg) {
    f32x4 accA = (f32x4){0.f, 0.f, 0.f, 0.f};
    f32x4 accB = (f32x4){0.f, 0.f, 0.f, 0.f};
#pragma unroll
    for (int kt = 0; kt < 7; ++kt) {
      bf16x8 hf = *(const bf16x8*)B_s[kt * 4 + q][rg * 16 + l16];
      accA = __builtin_amdgcn_mfma_f32_16x16x32_bf16(wfA[kt], hf, accA, 0, 0, 0);
      if (bvalid)
        accB = __builtin_amdgcn_mfma_f32_16x16x32_bf16(wfB[kt], hf, accB, 0, 0, 0);
    }
    const size_t row = (size_t)(r0 + rg * 16 + l16);
    {
      __half2 h01 = __floats2half2_rn(accA[0], accA[1]);
      __half2 h23 = __floats2half2_rn(accA[2], accA[3]);
      uint2 st; *(__half2*)&st.x = h01; *(__half2*)&st.y = h23;
      *(uint2*)(xg + row * G + 4 * jA) = st;
    }
    if (bvalid) {
      __half2 h01 = __floats2half2_rn(accB[0], accB[1]);
      __half2 h23 = __floats2half2_rn(accB[2], accB[3]);
      uint2 st; *(__half2*)&st.x = h01; *(__half2*)&st.y = h23;
      *(uint2*)(xg + row * G + 4 * jB) = st;
    }
  }
}

// ---- layer 1: MB1=2, 512 blocks x 512 thr (2 blocks/CU), waves 0..6 busy ---
__global__ __launch_bounds__(512, 4) void lstm_l1(
    const unsigned short* __restrict__ h0fT, const unsigned short* __restrict__ h0bT,
    const unsigned short* __restrict__ pk_hh, const unsigned short* __restrict__ pk1b,
    const __half* __restrict__ xg,
    const float* __restrict__ fc_w, const float* __restrict__ fc_b,
    float* __restrict__ out) {
  __shared__ __align__(16) short A_s[2][16][16][8];      // h1, K=128 (m 0..1 used)
  __shared__ __align__(16) short A2_s[28][16][8];        // epilogue [h0|1] K=224
  __shared__ float hf_s[MB1][H];
  __shared__ float hb_s[MB1][H];
  __shared__ float fcw_s[3 * D1];
  __shared__ float fcb_s[3];
  __shared__ float logit_s[MB1][3];

  const int tid = threadIdx.x;
  const int lane = tid & 63, w = tid >> 6;   // 8 waves
  const int q = lane >> 4, l16 = lane & 15;
  const int b0 = blockIdx.x * MB1;           // 512 blocks
  const uint2* xg2 = (const uint2*)xg;       // 100 uint2 per (t,b) row

  for (int i = tid; i < 2 * 16 * 16 * 8; i += 512) ((short*)A_s)[i] = 0;
  for (int i = tid; i < 25 * 16 * 8; i += 512) ((short*)A2_s)[i] = 0;  // kg 0..24
  for (int i = tid; i < 3 * 16 * 8; i += 512) {  // A2 kg25..27 zero + bias-one
    int jj = i & 7, gl = i >> 7;
    ((short*)&A2_s[25][0][0])[i] = (short)((gl == 0 && jj == 0) ? f2bf(1.f) : 0);
  }
  for (int i = tid; i < 3 * D1; i += 512) fcw_s[i] = fc_w[i];
  if (tid < 3) fcb_s[tid] = fc_b[tid];

  const bool busy = (w < 7);                 // waves 0..6 own tiles 4w..4w+3
  const int m = l16 & 1, g16 = (l16 >> 1) & 3;
  const int myMt = w * 4 + g16;
  const int jme = myMt * 4 + q;              // my element's j (>=100 invalid)
  // lanes l16>=8 duplicate l16-8 (same m,g16,q): mask their LDS writes
  const bool evalid = busy && (myMt < NT) && (l16 < 8);
  bool tv[4];
  bf16x8 wf[4][4];
  if (busy) {
#pragma unroll
    for (int i = 0; i < 4; ++i) {
      int mt = w * 4 + i; tv[i] = (mt < NT);
#pragma unroll
      for (int kt = 0; kt < 4; ++kt)
        wf[i][kt] = *(const bf16x8*)(pk_hh + ((size_t)(kt * 4 + q) * NP + mt * 16 + l16) * 8);
    }
  }
  float c = 0.f;
  // per-lane own-element xg, running pointer (+102400 uint2 per t);
  // invalid jme (<=111) reads <=96B past the row — lands in ws, unused.
  const uint2* xgp = xg2 + (size_t)(b0 + m) * 100 + jme;
  uint2 xgCur = {0, 0};
  if (busy) { xgCur = *xgp; xgp += Bsz * 100; }
  __syncthreads();

  int p = 0;
  for (int t = 0; t < Tt; ++t) {
    if (busy) {
      uint2 xgNxt = xgCur;
      if (t < Tt - 1) { xgNxt = *xgp; xgp += Bsz * 100; }
      bf16x8 hfrag[4];
#pragma unroll
      for (int kt = 0; kt < 4; ++kt) hfrag[kt] = *(const bf16x8*)A_s[p][kt * 4 + q][l16];
      f32x4 acc[4];
#pragma unroll
      for (int i = 0; i < 4; ++i) {
        acc[i] = (f32x4){0.f, 0.f, 0.f, 0.f};
        if (!tv[i]) continue;
#pragma unroll
        for (int kt = 0; kt < 4; ++kt)
          acc[i] = __builtin_amdgcn_mfma_f32_16x16x32_bf16(wf[i][kt], hfrag[kt], acc[i], 0, 0, 0);
      }
      // spread: all lanes swizzle unconditionally (src lane: same q, l16=m),
      // then 2-level select by g16; add own xg.
      float2 x01 = __half22float2(*(const __half2*)&xgCur.x);
      float2 x23 = __half22float2(*(const __half2*)&xgCur.y);
      float xr[4] = {x01.x, x01.y, x23.x, x23.y};
      float gr[4];
#pragma unroll
      for (int r = 0; r < 4; ++r) {
        float v0 = partner2(acc[0][r]);
        float v1 = partner2(acc[1][r]);
        float v2 = partner2(acc[2][r]);
        float v3 = partner2(acc[3][r]);
        float lo = (g16 & 1) ? v1 : v0;
        float hi = (g16 & 1) ? v3 : v2;
        gr[r] = ((g16 & 2) ? hi : lo) + xr[r];
      }
      float cc = sigm(gr[1]) * c + sigm(gr[0]) * tanhf_(gr[2]);
      c = cc;
      float h = sigm(gr[3]) * tanhf_(cc);
      if (evalid) {
        A_s[1 - p][jme >> 3][m][jme & 7] = (short)f2bf(h);
        if (t == Tt - 1) hf_s[m][jme] = h;
      }
      xgCur = xgNxt;
    }
    __syncthreads();
    p ^= 1;
  }

  // ---- layer-1 backward single step at t=T-1 (h=c=0) ----
  {
    const size_t base = ((size_t)(Tt - 1) * Bsz + b0) * H;
    if (tid < MB1 * 25) {  // stage rows m=0..1 only (this block's batch)
      int m2 = tid / 25, j0 = (tid - (tid / 25) * 25) * 4;
      *(uint2*)&A2_s[j0 >> 3][m2][j0 & 7] = *(const uint2*)(h0fT + base + m2 * H + j0);
      int k = 100 + j0;
      *(uint2*)&A2_s[k >> 3][m2][k & 7] = *(const uint2*)(h0bT + base + m2 * H + j0);
    }
  }
  __syncthreads();
  if (busy) {
    f32x4 acc[4];
#pragma unroll
    for (int i = 0; i < 4; ++i) acc[i] = (f32x4){0.f, 0.f, 0.f, 0.f};
#pragma unroll
    for (int kt = 0; kt < 7; ++kt) {
      bf16x8 hf = *(const bf16x8*)A2_s[kt * 4 + q][l16];
#pragma unroll
      for (int i = 0; i < 4; ++i) {
        if (!tv[i]) continue;
        int mt = w * 4 + i;
        bf16x8 wfb = *(const bf16x8*)(pk1b + ((size_t)(kt * 4 + q) * NP + mt * 16 + l16) * 8);
        acc[i] = __builtin_amdgcn_mfma_f32_16x16x32_bf16(wfb, hf, acc[i], 0, 0, 0);
      }
    }
    float gr[4];
#pragma unroll
    for (int r = 0; r < 4; ++r) {
      float v0 = partner2(acc[0][r]);
      float v1 = partner2(acc[1][r]);
      float v2 = partner2(acc[2][r]);
      float v3 = partner2(acc[3][r]);
      float lo = (g16 & 1) ? v1 : v0;
      float hi = (g16 & 1) ? v3 : v2;
      gr[r] = (g16 & 2) ? hi : lo;
    }
    float cc = sigm(gr[0]) * tanhf_(gr[2]);   // c_prev = 0
    if (evalid) hb_s[m][jme] = sigm(gr[3]) * tanhf_(cc);
  }
  __syncthreads();

  // ---- FC (3x200) + softmax ----
  if (tid < MB1 * 3) {
    int mr = tid / 3, cls = tid - mr * 3;
    float s = fcb_s[cls];
    for (int jj = 0; jj < H; ++jj) s += fcw_s[cls * D1 + jj] * hf_s[mr][jj];
    for (int jj = 0; jj < H; ++jj) s += fcw_s[cls * D1 + H + jj] * hb_s[mr][jj];
    logit_s[mr][cls] = s;
  }
  __syncthreads();
  if (tid < MB1) {
    float a = logit_s[tid][0], b = logit_s[tid][1], cc = logit_s[tid][2];
    float mx = fmaxf(a, fmaxf(b, cc));
    float e0 = __expf(a - mx), e1 = __expf(b - mx), e2 = __expf(cc - mx);
    float inv = 1.f / (e0 + e1 + e2);
    out[(b0 + tid) * 3 + 0] = e0 * inv;
    out[(b0 + tid) * 3 + 1] = e1 * inv;
    out[(b0 + tid) * 3 + 2] = e2 * inv;
  }
}

extern "C" void kernel_launch(void* const* d_in, const int* in_sizes, int n_in,
                              void* d_out, int out_size, void* d_ws, size_t ws_size,
                              hipStream_t stream) {
  const float* x        = (const float*)d_in[0];
  const float* w_ih_l0f = (const float*)d_in[1];
  const float* w_hh_l0f = (const float*)d_in[2];
  const float* b_ih_l0f = (const float*)d_in[3];
  const float* b_hh_l0f = (const float*)d_in[4];
  const float* w_ih_l0b = (const float*)d_in[5];
  const float* w_hh_l0b = (const float*)d_in[6];
  const float* b_ih_l0b = (const float*)d_in[7];
  const float* b_hh_l0b = (const float*)d_in[8];
  const float* w_ih_l1f = (const float*)d_in[9];
  const float* w_hh_l1f = (const float*)d_in[10];
  const float* b_ih_l1f = (const float*)d_in[11];
  const float* b_hh_l1f = (const float*)d_in[12];
  const float* w_ih_l1b = (const float*)d_in[13];
  // d_in[14] = w_hh_l1b unused (reverse dir at t=T-1 has h=0)
  const float* b_ih_l1b = (const float*)d_in[15];
  const float* b_hh_l1b = (const float*)d_in[16];
  const float* fc_w     = (const float*)d_in[17];
  const float* fc_b     = (const float*)d_in[18];

  unsigned short* h0fT = (unsigned short*)d_ws;
  unsigned short* h0bT = h0fT + (size_t)Tt * Bsz * H;
  __half* xgT          = (__half*)(h0bT + (size_t)Tt * Bsz * H);
  unsigned short* pk0f = (unsigned short*)(xgT + (size_t)Tt * Bsz * G);
  unsigned short* pk0b = pk0f + 16 * NP * 8;
  unsigned short* pkhh = pk0b + 16 * NP * 8;
  unsigned short* pkxg = pkhh + 16 * NP * 8;
  unsigned short* pk1b = pkxg + 28 * NP * 8;

  pack_all<<<dim3(448, 5), 256, 0, stream>>>(
      w_hh_l0f, w_ih_l0f, b_ih_l0f, b_hh_l0f,
      w_hh_l0b, w_ih_l0b, b_ih_l0b, b_hh_l0b,
      w_hh_l1f, b_ih_l1f, b_hh_l1f,
      w_ih_l1f, w_ih_l1b, b_ih_l1b, b_hh_l1b,
      pk0f, pk0b, pkhh, pkxg, pk1b);

  lstm_l0<<<dim3(Bsz / MB, 2), 512, 0, stream>>>(x, pk0f, pk0b, h0fT, h0bT);
  gemm_xg<<<(Bsz * Tt) / 64, 1024, 0, stream>>>(h0fT, h0bT, pkxg, xgT);
  lstm_l1<<<Bsz / MB1, 512, 0, stream>>>(h0fT, h0bT, pkhh, pk1b, xgT,
                                         fc_w, fc_b, (float*)d_out);
}

// Round 2
// 375.800 us; speedup vs baseline: 1.2593x; 1.2593x over previous
//
#include <hip/hip_runtime.h>
#include <hip/hip_fp16.h>

// LSTM_48850958024796 — R18: revert to R16 shapes (l0 1024thr/MB=8,
// l1 1024thr/MB1=4) + delete ALL ds_swizzles via dup-read:
// hfrag reads [l16&7] (l0) / [l16&3] (l1) duplicate batch rows into the
// previously-zero B columns, so each lane's own MFMA acc holds its gates
// (swizzle 0x17/0x13 src lane == l16&7/l16&3, same q -> provably equal).
// Spread becomes pure local cndmask select. Removes 64 (l0) / 112+16 (l1)
// LDS-pipe swizzle issues per CU-step from the latency-critical chain.
// R17 post-mortem: 2 blocks/CU overlap is real (MfmaUtil up) but MB=4
// restructure raised MFMA redundancy 2.56x->4.48x and 4x'd swizzles -> 473us.
// Falsified levers (do not retry): barrier_nv (neutral), unroll-2 (neg),
// mega-kernel+grid.sync (724), wave specialization one-kernel (spill, 877),
// small-MB block-split (R17, 473).
// Scan math (R3-proven): gates^T = W(A) @ [h|x|1]^T(B), cols gate-interleaved
// (n'=4j+gate). l0: MB=8, 2 tiles/wave up/down split. l1: MB1=4, 256 blocks,
// dense 4 tiles/wave (waves 0..6).

typedef __attribute__((ext_vector_type(8))) short bf16x8;
typedef __attribute__((ext_vector_type(4))) float f32x4;

constexpr int Bsz = 1024, Tt = 128, IN_ = 5, H = 100, G = 400, D1 = 200;
constexpr int NP = 512;   // packed gate cols (32 tiles of 16)
constexpr int NT = 25;    // real tiles (400/16)
constexpr int MB = 8;     // batch rows per block (l0)
constexpr int MB1 = 4;    // batch rows per block (l1)

__device__ __forceinline__ float sigm(float x)   { return 1.f / (1.f + __expf(-x)); }
__device__ __forceinline__ float tanhf_(float x) { return 1.f - 2.f / (__expf(2.f * x) + 1.f); }
__device__ __forceinline__ unsigned short f2bf(float f) {
  unsigned u = __float_as_uint(f);
  u += 0x7fff + ((u >> 16) & 1);
  return (unsigned short)(u >> 16);
}

// packed col n' (0..511): j=n'>>2, gate=n'&3, src row n = gate*100+j; j>=100->0
__device__ __forceinline__ void pack_body(
    const float* wA, int KA, const float* wB, int KB, int kbo,
    const float* b1, const float* b2, int bias_k,
    unsigned short* dst, int Kg, int idx) {
  if (idx >= Kg * NP * 8) return;
  int jj = idx & 7, rest = idx >> 3;
  int np_ = rest % NP, g = rest / NP;
  int j = np_ >> 2, gate = np_ & 3;
  int k = g * 8 + jj;
  float v = 0.f;
  if (j < H) {
    int n = gate * H + j;
    if (k < KA) v = wA[n * KA + k];
    else if (KB > 0 && k >= kbo && k < kbo + KB) v = wB[n * KB + (k - kbo)];
    else if (k == bias_k) v = b1[n] + b2[n];
  }
  dst[idx] = f2bf(v);
}

__global__ void pack_all(
    const float* __restrict__ w_hh_l0f, const float* __restrict__ w_ih_l0f,
    const float* __restrict__ b_ih_l0f, const float* __restrict__ b_hh_l0f,
    const float* __restrict__ w_hh_l0b, const float* __restrict__ w_ih_l0b,
    const float* __restrict__ b_ih_l0b, const float* __restrict__ b_hh_l0b,
    const float* __restrict__ w_hh_l1f, const float* __restrict__ b_ih_l1f,
    const float* __restrict__ b_hh_l1f,
    const float* __restrict__ w_ih_l1f, const float* __restrict__ w_ih_l1b,
    const float* __restrict__ b_ih_l1b, const float* __restrict__ b_hh_l1b,
    unsigned short* __restrict__ pk0f, unsigned short* __restrict__ pk0b,
    unsigned short* __restrict__ pkhh, unsigned short* __restrict__ pkxg,
    unsigned short* __restrict__ pk1b) {
  int idx = blockIdx.x * 256 + threadIdx.x;
  switch (blockIdx.y) {
    case 0: pack_body(w_hh_l0f, 100, w_ih_l0f, 5, 100, b_ih_l0f, b_hh_l0f, 105, pk0f, 16, idx); break;
    case 1: pack_body(w_hh_l0b, 100, w_ih_l0b, 5, 100, b_ih_l0b, b_hh_l0b, 105, pk0b, 16, idx); break;
    case 2: pack_body(w_hh_l1f, 100, nullptr, 0, 0, b_ih_l1f, b_hh_l1f, -1, pkhh, 16, idx); break;
    case 3: pack_body(w_ih_l1f, 200, nullptr, 0, 0, b_ih_l1f, b_hh_l1f, 200, pkxg, 28, idx); break;
    default: pack_body(w_ih_l1b, 200, nullptr, 0, 0, b_ih_l1b, b_hh_l1b, 200, pk1b, 28, idx);
  }
}

// ------------- layer 0 scan (grid = 128 x 2 dirs, 1024 thr) -----------------
__global__ __launch_bounds__(1024, 1) void lstm_l0(
    const float* __restrict__ x,
    const unsigned short* __restrict__ pk_f, const unsigned short* __restrict__ pk_b,
    unsigned short* __restrict__ h0fT, unsigned short* __restrict__ h0bT) {
  __shared__ __align__(16) short A_s[2][16][16][8];  // [buf][kg][m16][jj], K=128

  const int tid = threadIdx.x;
  const int lane = tid & 63, w = tid >> 6;       // 16 waves
  const int q = lane >> 4, l16 = lane & 15;
  const int b0 = blockIdx.x * MB;
  const int dir = blockIdx.y;
  const unsigned short* pk = dir ? pk_b : pk_f;
  unsigned short* hT = dir ? h0bT : h0fT;

  for (int i = tid; i < 2 * 16 * 16 * 8; i += 1024) ((short*)A_s)[i] = 0;

  const int mtA = w, mtB = w + 16;
  const bool bvalid = (mtB < NT);
  bf16x8 wfA[4], wfB[4];
#pragma unroll
  for (int kt = 0; kt < 4; ++kt) {
    wfA[kt] = *(const bf16x8*)(pk + ((size_t)(kt * 4 + q) * NP + mtA * 16 + l16) * 8);
    wfB[kt] = *(const bf16x8*)(pk + ((size_t)(kt * 4 + q) * NP + mtB * 16 + l16) * 8);
  }
  float c = 0.f;
  const bool up = (l16 >= 8);
  const int mm = l16 & 7;
  const int j = (up ? mtB : mtA) * 4 + q;
  const bool valid = up ? bvalid : true;
  const int xm = tid / IN_, xe = tid - xm * IN_;              // x loader (tid<40)
  const int sm = tid / 25, sj = (tid - (tid / 25) * 25) * 4;  // h store (tid<200)
  const float* xp = x + ((size_t)(b0 + xm) * Tt + (dir ? Tt - 2 : 1)) * IN_ + xe;
  const int xstride = dir ? -IN_ : IN_;
  unsigned short* hp =
      hT + ((size_t)(dir ? Tt - 1 : 0) * Bsz + b0 + sm) * H + sj;
  const int hstride = dir ? -(Bsz * H) : (Bsz * H);
  __syncthreads();
  if (tid < 16) {  // bias-one col k=105 (kg13,jj1), both bufs
    A_s[0][13][tid][1] = (short)f2bf(1.f);
    A_s[1][13][tid][1] = (short)f2bf(1.f);
  }
  if (tid < MB * IN_) {  // x(t_first) -> buf0, direct f32 read
    int t0 = dir ? (Tt - 1) : 0;
    int k = 100 + xe;
    A_s[0][k >> 3][xm][k & 7] =
        (short)f2bf(x[((size_t)(b0 + xm) * Tt + t0) * IN_ + xe]);
  }
  __syncthreads();

  int p = 0;
  for (int step = 0; step < Tt; ++step) {
    if (step > 0 && tid < 200) {  // coalesced store of h(prev) from buf p
      uint2 hv = *(const uint2*)&A_s[p][sj >> 3][sm][sj & 7];
      *(uint2*)hp = hv;
      hp += hstride;
    }
    float xn = 0.f;
    const bool do_x = (tid < MB * IN_) && (step < Tt - 1);
    if (do_x) { xn = *xp; xp += xstride; }
    bf16x8 hfrag[4];
    // dup-read: rows 0..7 duplicated into B cols 8..15 (same-addr broadcast).
    // Each lane's own acc then holds gates for batch row l16&7 -> no swizzle.
#pragma unroll
    for (int kt = 0; kt < 4; ++kt) hfrag[kt] = *(const bf16x8*)A_s[p][kt * 4 + q][l16 & 7];
    f32x4 accA = (f32x4){0.f, 0.f, 0.f, 0.f};
    f32x4 accB = (f32x4){0.f, 0.f, 0.f, 0.f};
#pragma unroll
    for (int kt = 0; kt < 4; ++kt)
      accA = __builtin_amdgcn_mfma_f32_16x16x32_bf16(wfA[kt], hfrag[kt], accA, 0, 0, 0);
    if (bvalid) {
#pragma unroll
      for (int kt = 0; kt < 4; ++kt)
        accB = __builtin_amdgcn_mfma_f32_16x16x32_bf16(wfB[kt], hfrag[kt], accB, 0, 0, 0);
    }
    float g0 = up ? accB[0] : accA[0];
    float g1 = up ? accB[1] : accA[1];
    float g2 = up ? accB[2] : accA[2];
    float g3 = up ? accB[3] : accA[3];
    float cc = sigm(g1) * c + sigm(g0) * tanhf_(g2);
    c = cc;
    float h = sigm(g3) * tanhf_(cc);
    if (valid) A_s[1 - p][j >> 3][mm][j & 7] = (short)f2bf(h);
    if (do_x) {
      int k = 100 + xe;
      A_s[1 - p][k >> 3][xm][k & 7] = (short)f2bf(xn);
    }
    __syncthreads();
    p ^= 1;
  }
  if (tid < 200) *(uint2*)hp = *(const uint2*)&A_s[p][sj >> 3][sm][sj & 7];  // final h
}

// ---- xgT[t*1024+b][400] = [h0f|h0b] @ W_ih_l1f^T + bias (fp16, interleaved) --
__global__ __launch_bounds__(1024, 1) void gemm_xg(
    const unsigned short* __restrict__ h0fT, const unsigned short* __restrict__ h0bT,
    const unsigned short* __restrict__ pkw, __half* __restrict__ xg) {
  __shared__ __align__(16) short B_s[28][64][8];  // K=224 aug (k=200 bias-one)
  const int tid = threadIdx.x;
  const int lane = tid & 63, w = tid >> 6;   // 16 waves
  const int q = lane >> 4, l16 = lane & 15;
  const int r0 = blockIdx.x * 64;            // rows r = t*1024+b
  const size_t base = (size_t)r0 * H;

  for (int i = tid; i < 3 * 64 * 8; i += 1024) {  // kg 25..27: zero + bias-one
    int jj = i & 7, gl = i >> 9;
    ((short*)&B_s[25][0][0])[i] = (short)((gl == 0 && jj == 0) ? f2bf(1.f) : 0);
  }
  for (int idx = tid; idx < 1600; idx += 1024) {  // h0f k=0..99, h0b k=100..199
    int m = idx / 25, j0 = (idx - (idx / 25) * 25) * 4;
    *(uint2*)&B_s[j0 >> 3][m][j0 & 7] = *(const uint2*)(h0fT + base + m * H + j0);
    int k = 100 + j0;
    *(uint2*)&B_s[k >> 3][m][k & 7] = *(const uint2*)(h0bT + base + m * H + j0);
  }

  const int mtA = w, mtB = w + 16;
  const bool bvalid = (mtB < NT);
  bf16x8 wfA[7], wfB[7];
#pragma unroll
  for (int kt = 0; kt < 7; ++kt) {
    wfA[kt] = *(const bf16x8*)(pkw + ((size_t)(kt * 4 + q) * NP + mtA * 16 + l16) * 8);
    wfB[kt] = *(const bf16x8*)(pkw + ((size_t)(kt * 4 + q) * NP + mtB * 16 + l16) * 8);
  }
  const int jA = mtA * 4 + q, jB = mtB * 4 + q;
  __syncthreads();

#pragma unroll
  for (int rg = 0; rg < 4; ++rg) {
    f32x4 accA = (f32x4){0.f, 0.f, 0.f, 0.f};
    f32x4 accB = (f32x4){0.f, 0.f, 0.f, 0.f};
#pragma unroll
    for (int kt = 0; kt < 7; ++kt) {
      bf16x8 hf = *(const bf16x8*)B_s[kt * 4 + q][rg * 16 + l16];
      accA = __builtin_amdgcn_mfma_f32_16x16x32_bf16(wfA[kt], hf, accA, 0, 0, 0);
      if (bvalid)
        accB = __builtin_amdgcn_mfma_f32_16x16x32_bf16(wfB[kt], hf, accB, 0, 0, 0);
    }
    const size_t row = (size_t)(r0 + rg * 16 + l16);
    {
      __half2 h01 = __floats2half2_rn(accA[0], accA[1]);
      __half2 h23 = __floats2half2_rn(accA[2], accA[3]);
      uint2 st; *(__half2*)&st.x = h01; *(__half2*)&st.y = h23;
      *(uint2*)(xg + row * G + 4 * jA) = st;
    }
    if (bvalid) {
      __half2 h01 = __floats2half2_rn(accB[0], accB[1]);
      __half2 h23 = __floats2half2_rn(accB[2], accB[3]);
      uint2 st; *(__half2*)&st.x = h01; *(__half2*)&st.y = h23;
      *(uint2*)(xg + row * G + 4 * jB) = st;
    }
  }
}

// ---- layer 1: MB1=4, 256 blocks, dense 4 tiles/wave (waves 0..6 busy) ------
__global__ __launch_bounds__(1024, 1) void lstm_l1(
    const unsigned short* __restrict__ h0fT, const unsigned short* __restrict__ h0bT,
    const unsigned short* __restrict__ pk_hh, const unsigned short* __restrict__ pk1b,
    const __half* __restrict__ xg,
    const float* __restrict__ fc_w, const float* __restrict__ fc_b,
    float* __restrict__ out) {
  __shared__ __align__(16) short A_s[2][16][16][8];      // h1, K=128 (m 0..3 used)
  __shared__ __align__(16) short A2_s[28][16][8];        // epilogue [h0|1] K=224
  __shared__ float hf_s[MB1][H];
  __shared__ float hb_s[MB1][H];
  __shared__ float fcw_s[3 * D1];
  __shared__ float fcb_s[3];
  __shared__ float logit_s[MB1][3];

  const int tid = threadIdx.x;
  const int lane = tid & 63, w = tid >> 6;   // 16 waves
  const int q = lane >> 4, l16 = lane & 15;
  const int b0 = blockIdx.x * MB1;           // 256 blocks
  const uint2* xg2 = (const uint2*)xg;       // 100 uint2 per (t,b) row

  for (int i = tid; i < 2 * 16 * 16 * 8; i += 1024) ((short*)A_s)[i] = 0;
  for (int i = tid; i < 25 * 16 * 8; i += 1024) ((short*)A2_s)[i] = 0;  // kg 0..24
  for (int i = tid; i < 3 * 16 * 8; i += 1024) {  // A2 kg25..27 zero + bias-one
    int jj = i & 7, gl = i >> 7;
    ((short*)&A2_s[25][0][0])[i] = (short)((gl == 0 && jj == 0) ? f2bf(1.f) : 0);
  }
  for (int i = tid; i < 3 * D1; i += 1024) fcw_s[i] = fc_w[i];
  if (tid < 3) fcb_s[tid] = fc_b[tid];

  const bool busy = (w < 7);                 // waves 0..6 own tiles 4w..4w+3
  const int m = l16 & 3, g16 = l16 >> 2;
  const int myMt = w * 4 + g16;
  const int jme = myMt * 4 + q;              // my element's j (>=100 invalid)
  const bool evalid = busy && (myMt < NT);
  int mts[4]; bool tv[4];
  bf16x8 wf[4][4];
  if (busy) {
#pragma unroll
    for (int i = 0; i < 4; ++i) {
      int mt = w * 4 + i; mts[i] = mt; tv[i] = (mt < NT);
#pragma unroll
      for (int kt = 0; kt < 4; ++kt)
        wf[i][kt] = *(const bf16x8*)(pk_hh + ((size_t)(kt * 4 + q) * NP + mt * 16 + l16) * 8);
    }
  }
  float c = 0.f;
  // per-lane own-element xg, running pointer (+102400 uint2 per t);
  // invalid jme (<=111) reads <=96B past the row — lands in ws, unused.
  const uint2* xgp = xg2 + (size_t)(b0 + m) * 100 + jme;
  uint2 xgCur = {0, 0};
  if (busy) { xgCur = *xgp; xgp += Bsz * 100; }
  __syncthreads();

  int p = 0;
  for (int t = 0; t < Tt; ++t) {
    if (busy) {
      uint2 xgNxt = xgCur;
      if (t < Tt - 1) { xgNxt = *xgp; xgp += Bsz * 100; }
      bf16x8 hfrag[4];
      // dup-read: rows 0..3 duplicated into B cols 4..15 -> each lane's own
      // acc[i] holds gates for batch row l16&3; spread = local select.
#pragma unroll
      for (int kt = 0; kt < 4; ++kt) hfrag[kt] = *(const bf16x8*)A_s[p][kt * 4 + q][l16 & 3];
      f32x4 acc[4];
#pragma unroll
      for (int i = 0; i < 4; ++i) {
        acc[i] = (f32x4){0.f, 0.f, 0.f, 0.f};
        if (!tv[i]) continue;
#pragma unroll
        for (int kt = 0; kt < 4; ++kt)
          acc[i] = __builtin_amdgcn_mfma_f32_16x16x32_bf16(wf[i][kt], hfrag[kt], acc[i], 0, 0, 0);
      }
      float2 x01 = __half22float2(*(const __half2*)&xgCur.x);
      float2 x23 = __half22float2(*(const __half2*)&xgCur.y);
      float xr[4] = {x01.x, x01.y, x23.x, x23.y};
      float gr[4];
#pragma unroll
      for (int r = 0; r < 4; ++r) {
        float lo = (g16 & 1) ? acc[1][r] : acc[0][r];
        float hi = (g16 & 1) ? acc[3][r] : acc[2][r];
        gr[r] = ((g16 & 2) ? hi : lo) + xr[r];
      }
      float cc = sigm(gr[1]) * c + sigm(gr[0]) * tanhf_(gr[2]);
      c = cc;
      float h = sigm(gr[3]) * tanhf_(cc);
      if (evalid) {
        A_s[1 - p][jme >> 3][m][jme & 7] = (short)f2bf(h);
        if (t == Tt - 1) hf_s[m][jme] = h;
      }
      xgCur = xgNxt;
    }
    __syncthreads();
    p ^= 1;
  }

  // ---- layer-1 backward single step at t=T-1 (h=c=0) ----
  {
    const size_t base = ((size_t)(Tt - 1) * Bsz + b0) * H;
    if (tid < 100) {  // stage rows m=0..3 only (this block's batch)
      int m2 = tid / 25, j0 = (tid - (tid / 25) * 25) * 4;
      *(uint2*)&A2_s[j0 >> 3][m2][j0 & 7] = *(const uint2*)(h0fT + base + m2 * H + j0);
      int k = 100 + j0;
      *(uint2*)&A2_s[k >> 3][m2][k & 7] = *(const uint2*)(h0bT + base + m2 * H + j0);
    }
  }
  __syncthreads();
  if (busy) {
    f32x4 acc[4];
#pragma unroll
    for (int i = 0; i < 4; ++i) acc[i] = (f32x4){0.f, 0.f, 0.f, 0.f};
#pragma unroll
    for (int kt = 0; kt < 7; ++kt) {
      bf16x8 hf = *(const bf16x8*)A2_s[kt * 4 + q][l16 & 3];  // dup-read
#pragma unroll
      for (int i = 0; i < 4; ++i) {
        if (!tv[i]) continue;
        bf16x8 wfb = *(const bf16x8*)(pk1b + ((size_t)(kt * 4 + q) * NP + mts[i] * 16 + l16) * 8);
        acc[i] = __builtin_amdgcn_mfma_f32_16x16x32_bf16(wfb, hf, acc[i], 0, 0, 0);
      }
    }
    float gr[4];
#pragma unroll
    for (int r = 0; r < 4; ++r) {
      float lo = (g16 & 1) ? acc[1][r] : acc[0][r];
      float hi = (g16 & 1) ? acc[3][r] : acc[2][r];
      gr[r] = (g16 & 2) ? hi : lo;
    }
    float cc = sigm(gr[0]) * tanhf_(gr[2]);   // c_prev = 0
    if (evalid) hb_s[m][jme] = sigm(gr[3]) * tanhf_(cc);
  }
  __syncthreads();

  // ---- FC (3x200) + softmax ----
  if (tid < MB1 * 3) {
    int mr = tid / 3, cls = tid - mr * 3;
    float s = fcb_s[cls];
    for (int jj = 0; jj < H; ++jj) s += fcw_s[cls * D1 + jj] * hf_s[mr][jj];
    for (int jj = 0; jj < H; ++jj) s += fcw_s[cls * D1 + H + jj] * hb_s[mr][jj];
    logit_s[mr][cls] = s;
  }
  __syncthreads();
  if (tid < MB1) {
    float a = logit_s[tid][0], b = logit_s[tid][1], cc = logit_s[tid][2];
    float mx = fmaxf(a, fmaxf(b, cc));
    float e0 = __expf(a - mx), e1 = __expf(b - mx), e2 = __expf(cc - mx);
    float inv = 1.f / (e0 + e1 + e2);
    out[(b0 + tid) * 3 + 0] = e0 * inv;
    out[(b0 + tid) * 3 + 1] = e1 * inv;
    out[(b0 + tid) * 3 + 2] = e2 * inv;
  }
}

extern "C" void kernel_launch(void* const* d_in, const int* in_sizes, int n_in,
                              void* d_out, int out_size, void* d_ws, size_t ws_size,
                              hipStream_t stream) {
  const float* x        = (const float*)d_in[0];
  const float* w_ih_l0f = (const float*)d_in[1];
  const float* w_hh_l0f = (const float*)d_in[2];
  const float* b_ih_l0f = (const float*)d_in[3];
  const float* b_hh_l0f = (const float*)d_in[4];
  const float* w_ih_l0b = (const float*)d_in[5];
  const float* w_hh_l0b = (const float*)d_in[6];
  const float* b_ih_l0b = (const float*)d_in[7];
  const float* b_hh_l0b = (const float*)d_in[8];
  const float* w_ih_l1f = (const float*)d_in[9];
  const float* w_hh_l1f = (const float*)d_in[10];
  const float* b_ih_l1f = (const float*)d_in[11];
  const float* b_hh_l1f = (const float*)d_in[12];
  const float* w_ih_l1b = (const float*)d_in[13];
  // d_in[14] = w_hh_l1b unused (reverse dir at t=T-1 has h=0)
  const float* b_ih_l1b = (const float*)d_in[15];
  const float* b_hh_l1b = (const float*)d_in[16];
  const float* fc_w     = (const float*)d_in[17];
  const float* fc_b     = (const float*)d_in[18];

  unsigned short* h0fT = (unsigned short*)d_ws;
  unsigned short* h0bT = h0fT + (size_t)Tt * Bsz * H;
  __half* xgT          = (__half*)(h0bT + (size_t)Tt * Bsz * H);
  unsigned short* pk0f = (unsigned short*)(xgT + (size_t)Tt * Bsz * G);
  unsigned short* pk0b = pk0f + 16 * NP * 8;
  unsigned short* pkhh = pk0b + 16 * NP * 8;
  unsigned short* pkxg = pkhh + 16 * NP * 8;
  unsigned short* pk1b = pkxg + 28 * NP * 8;

  pack_all<<<dim3(448, 5), 256, 0, stream>>>(
      w_hh_l0f, w_ih_l0f, b_ih_l0f, b_hh_l0f,
      w_hh_l0b, w_ih_l0b, b_ih_l0b, b_hh_l0b,
      w_hh_l1f, b_ih_l1f, b_hh_l1f,
      w_ih_l1f, w_ih_l1b, b_ih_l1b, b_hh_l1b,
      pk0f, pk0b, pkhh, pkxg, pk1b);

  lstm_l0<<<dim3(Bsz / MB, 2), 1024, 0, stream>>>(x, pk0f, pk0b, h0fT, h0bT);
  gemm_xg<<<(Bsz * Tt) / 64, 1024, 0, stream>>>(h0fT, h0bT, pkxg, xgT);
  lstm_l1<<<Bsz / MB1, 1024, 0, stream>>>(h0fT, h0bT, pkhh, pk1b, xgT,
                                          fc_w, fc_b, (float*)d_out);
}

// Round 3
// 358.373 us; speedup vs baseline: 1.3205x; 1.0486x over previous
//
#include <hip/hip_runtime.h>
#include <hip/hip_fp16.h>

// LSTM_48850958024796 — R19: keep swizzle-free select (R18) but move batch-row
// duplication from READ-time to WRITE-time. R18's dup-read [l16&7] made b128
// lane-pairs hit the SAME address -> no broadcast for b128 on gfx950 ->
// SQ_LDS_BANK_CONFLICT 2.65M->11.04M, l0 134->140us. Now: h/x written to both
// col m and mirror cols (1 extra ds_write_b16 l0, 3 l1, off the read path);
// hfrag reads restored to [l16] (distinct addrs, 2-way bank alias = free).
// gemm_xg: 512 resident blocks x 4 row-groups, double-buffered LDS + async
// stage (issue-early/commit-late, T14) -> hides the 25.6KB staging latency
// that 2048 one-shot blocks serially exposed; pkw frags loaded 1x per block.
// Falsified levers (do not retry): barrier_nv (neutral), unroll-2 (neg),
// mega-kernel+grid.sync (724), wave specialization one-kernel (spill, 877),
// small-MB block-split (R17, 473), dup-READ b128 (R18, +6us l0).
// Scan math (R3-proven): gates^T = W(A) @ [h|x|1]^T(B), cols gate-interleaved
// (n'=4j+gate). l0: MB=8, 2 tiles/wave up/down split. l1: MB1=4, 256 blocks,
// dense 4 tiles/wave (waves 0..6).

typedef __attribute__((ext_vector_type(8))) short bf16x8;
typedef __attribute__((ext_vector_type(4))) float f32x4;

constexpr int Bsz = 1024, Tt = 128, IN_ = 5, H = 100, G = 400, D1 = 200;
constexpr int NP = 512;   // packed gate cols (32 tiles of 16)
constexpr int NT = 25;    // real tiles (400/16)
constexpr int MB = 8;     // batch rows per block (l0)
constexpr int MB1 = 4;    // batch rows per block (l1)
constexpr int NGRP = 4;   // row-groups per gemm_xg block
constexpr int GSTRIDE = 512;  // gemm_xg grid size

__device__ __forceinline__ float sigm(float x)   { return 1.f / (1.f + __expf(-x)); }
__device__ __forceinline__ float tanhf_(float x) { return 1.f - 2.f / (__expf(2.f * x) + 1.f); }
__device__ __forceinline__ unsigned short f2bf(float f) {
  unsigned u = __float_as_uint(f);
  u += 0x7fff + ((u >> 16) & 1);
  return (unsigned short)(u >> 16);
}

// packed col n' (0..511): j=n'>>2, gate=n'&3, src row n = gate*100+j; j>=100->0
__device__ __forceinline__ void pack_body(
    const float* wA, int KA, const float* wB, int KB, int kbo,
    const float* b1, const float* b2, int bias_k,
    unsigned short* dst, int Kg, int idx) {
  if (idx >= Kg * NP * 8) return;
  int jj = idx & 7, rest = idx >> 3;
  int np_ = rest % NP, g = rest / NP;
  int j = np_ >> 2, gate = np_ & 3;
  int k = g * 8 + jj;
  float v = 0.f;
  if (j < H) {
    int n = gate * H + j;
    if (k < KA) v = wA[n * KA + k];
    else if (KB > 0 && k >= kbo && k < kbo + KB) v = wB[n * KB + (k - kbo)];
    else if (k == bias_k) v = b1[n] + b2[n];
  }
  dst[idx] = f2bf(v);
}

__global__ void pack_all(
    const float* __restrict__ w_hh_l0f, const float* __restrict__ w_ih_l0f,
    const float* __restrict__ b_ih_l0f, const float* __restrict__ b_hh_l0f,
    const float* __restrict__ w_hh_l0b, const float* __restrict__ w_ih_l0b,
    const float* __restrict__ b_ih_l0b, const float* __restrict__ b_hh_l0b,
    const float* __restrict__ w_hh_l1f, const float* __restrict__ b_ih_l1f,
    const float* __restrict__ b_hh_l1f,
    const float* __restrict__ w_ih_l1f, const float* __restrict__ w_ih_l1b,
    const float* __restrict__ b_ih_l1b, const float* __restrict__ b_hh_l1b,
    unsigned short* __restrict__ pk0f, unsigned short* __restrict__ pk0b,
    unsigned short* __restrict__ pkhh, unsigned short* __restrict__ pkxg,
    unsigned short* __restrict__ pk1b) {
  int idx = blockIdx.x * 256 + threadIdx.x;
  switch (blockIdx.y) {
    case 0: pack_body(w_hh_l0f, 100, w_ih_l0f, 5, 100, b_ih_l0f, b_hh_l0f, 105, pk0f, 16, idx); break;
    case 1: pack_body(w_hh_l0b, 100, w_ih_l0b, 5, 100, b_ih_l0b, b_hh_l0b, 105, pk0b, 16, idx); break;
    case 2: pack_body(w_hh_l1f, 100, nullptr, 0, 0, b_ih_l1f, b_hh_l1f, -1, pkhh, 16, idx); break;
    case 3: pack_body(w_ih_l1f, 200, nullptr, 0, 0, b_ih_l1f, b_hh_l1f, 200, pkxg, 28, idx); break;
    default: pack_body(w_ih_l1b, 200, nullptr, 0, 0, b_ih_l1b, b_hh_l1b, 200, pk1b, 28, idx);
  }
}

// ------------- layer 0 scan (grid = 128 x 2 dirs, 1024 thr) -----------------
__global__ __launch_bounds__(1024, 1) void lstm_l0(
    const float* __restrict__ x,
    const unsigned short* __restrict__ pk_f, const unsigned short* __restrict__ pk_b,
    unsigned short* __restrict__ h0fT, unsigned short* __restrict__ h0bT) {
  __shared__ __align__(16) short A_s[2][16][16][8];  // [buf][kg][m16][jj], K=128

  const int tid = threadIdx.x;
  const int lane = tid & 63, w = tid >> 6;       // 16 waves
  const int q = lane >> 4, l16 = lane & 15;
  const int b0 = blockIdx.x * MB;
  const int dir = blockIdx.y;
  const unsigned short* pk = dir ? pk_b : pk_f;
  unsigned short* hT = dir ? h0bT : h0fT;

  for (int i = tid; i < 2 * 16 * 16 * 8; i += 1024) ((short*)A_s)[i] = 0;

  const int mtA = w, mtB = w + 16;
  const bool bvalid = (mtB < NT);
  bf16x8 wfA[4], wfB[4];
#pragma unroll
  for (int kt = 0; kt < 4; ++kt) {
    wfA[kt] = *(const bf16x8*)(pk + ((size_t)(kt * 4 + q) * NP + mtA * 16 + l16) * 8);
    wfB[kt] = *(const bf16x8*)(pk + ((size_t)(kt * 4 + q) * NP + mtB * 16 + l16) * 8);
  }
  float c = 0.f;
  const bool up = (l16 >= 8);
  const int mm = l16 & 7;
  const int j = (up ? mtB : mtA) * 4 + q;
  const bool valid = up ? bvalid : true;
  const int xm = tid / IN_, xe = tid - xm * IN_;              // x loader (tid<40)
  const int sm = tid / 25, sj = (tid - (tid / 25) * 25) * 4;  // h store (tid<200)
  const float* xp = x + ((size_t)(b0 + xm) * Tt + (dir ? Tt - 2 : 1)) * IN_ + xe;
  const int xstride = dir ? -IN_ : IN_;
  unsigned short* hp =
      hT + ((size_t)(dir ? Tt - 1 : 0) * Bsz + b0 + sm) * H + sj;
  const int hstride = dir ? -(Bsz * H) : (Bsz * H);
  __syncthreads();
  if (tid < 16) {  // bias-one col k=105 (kg13,jj1), both bufs, all 16 cols
    A_s[0][13][tid][1] = (short)f2bf(1.f);
    A_s[1][13][tid][1] = (short)f2bf(1.f);
  }
  if (tid < MB * IN_) {  // x(t_first) -> buf0, direct f32 read, write-dup
    int t0 = dir ? (Tt - 1) : 0;
    int k = 100 + xe;
    short xv = (short)f2bf(x[((size_t)(b0 + xm) * Tt + t0) * IN_ + xe]);
    A_s[0][k >> 3][xm][k & 7] = xv;
    A_s[0][k >> 3][xm + 8][k & 7] = xv;
  }
  __syncthreads();

  int p = 0;
  for (int step = 0; step < Tt; ++step) {
    if (step > 0 && tid < 200) {  // coalesced store of h(prev) from buf p
      uint2 hv = *(const uint2*)&A_s[p][sj >> 3][sm][sj & 7];
      *(uint2*)hp = hv;
      hp += hstride;
    }
    float xn = 0.f;
    const bool do_x = (tid < MB * IN_) && (step < Tt - 1);
    if (do_x) { xn = *xp; xp += xstride; }
    bf16x8 hfrag[4];
    // [l16] read: distinct addr per lane (2-way bank alias free); cols 8..15
    // hold write-time duplicates of rows 0..7 -> own acc has own gates.
#pragma unroll
    for (int kt = 0; kt < 4; ++kt) hfrag[kt] = *(const bf16x8*)A_s[p][kt * 4 + q][l16];
    f32x4 accA = (f32x4){0.f, 0.f, 0.f, 0.f};
    f32x4 accB = (f32x4){0.f, 0.f, 0.f, 0.f};
#pragma unroll
    for (int kt = 0; kt < 4; ++kt)
      accA = __builtin_amdgcn_mfma_f32_16x16x32_bf16(wfA[kt], hfrag[kt], accA, 0, 0, 0);
    if (bvalid) {
#pragma unroll
      for (int kt = 0; kt < 4; ++kt)
        accB = __builtin_amdgcn_mfma_f32_16x16x32_bf16(wfB[kt], hfrag[kt], accB, 0, 0, 0);
    }
    float g0 = up ? accB[0] : accA[0];
    float g1 = up ? accB[1] : accA[1];
    float g2 = up ? accB[2] : accA[2];
    float g3 = up ? accB[3] : accA[3];
    float cc = sigm(g1) * c + sigm(g0) * tanhf_(g2);
    c = cc;
    float h = sigm(g3) * tanhf_(cc);
    if (valid) {  // write-dup: col mm and mirror col mm+8
      short hh = (short)f2bf(h);
      A_s[1 - p][j >> 3][mm][j & 7] = hh;
      A_s[1 - p][j >> 3][mm + 8][j & 7] = hh;
    }
    if (do_x) {
      int k = 100 + xe;
      short xv = (short)f2bf(xn);
      A_s[1 - p][k >> 3][xm][k & 7] = xv;
      A_s[1 - p][k >> 3][xm + 8][k & 7] = xv;
    }
    __syncthreads();
    p ^= 1;
  }
  if (tid < 200) *(uint2*)hp = *(const uint2*)&A_s[p][sj >> 3][sm][sj & 7];  // final h
}

// ---- xgT[t*1024+b][400] = [h0f|h0b] @ W_ih_l1f^T + bias (fp16, interleaved) --
// 512 resident blocks x NGRP=4 row-groups, double-buffered LDS, async stage.
__global__ __launch_bounds__(1024, 1) void gemm_xg(
    const unsigned short* __restrict__ h0fT, const unsigned short* __restrict__ h0bT,
    const unsigned short* __restrict__ pkw, __half* __restrict__ xg) {
  __shared__ __align__(16) short B_s[2][28][64][8];  // K=224 aug (k=200 bias-one)
  const int tid = threadIdx.x;
  const int lane = tid & 63, w = tid >> 6;   // 16 waves
  const int q = lane >> 4, l16 = lane & 15;

  // static init: kg 25..27 both buffers (zero + bias-one at k=200, jj=0)
#pragma unroll
  for (int b = 0; b < 2; ++b)
    for (int i = tid; i < 3 * 64 * 8; i += 1024) {
      int jj = i & 7, gl = i >> 9;
      ((short*)&B_s[b][25][0][0])[i] = (short)((gl == 0 && jj == 0) ? f2bf(1.f) : 0);
    }

  const int mtA = w, mtB = w + 16;
  const bool bvalid = (mtB < NT);
  bf16x8 wfA[7], wfB[7];
#pragma unroll
  for (int kt = 0; kt < 7; ++kt) {
    wfA[kt] = *(const bf16x8*)(pkw + ((size_t)(kt * 4 + q) * NP + mtA * 16 + l16) * 8);
    wfB[kt] = *(const bf16x8*)(pkw + ((size_t)(kt * 4 + q) * NP + mtB * 16 + l16) * 8);
  }
  const int jA = mtA * 4 + q, jB = mtB * 4 + q;

  // staging tasks: idx -> (m=idx/25, j0=(idx%25)*4); tid owns idx=tid and
  // (tid<576) idx=tid+1024. 1600 tasks stage 64 rows x [h0f|h0b].
  const int t0m = tid / 25, t0j = (tid - t0m * 25) * 4;
  const int t1 = tid + 1024;
  const int t1m = t1 / 25, t1j = (t1 - t1m * 25) * 4;
  uint2 sf0, sb0, sf1, sb1;

#define XG_ISSUE(GRP)                                                  \
  {                                                                    \
    size_t base_ = (size_t)(GRP)*64 * H;                               \
    sf0 = *(const uint2*)(h0fT + base_ + t0m * H + t0j);               \
    sb0 = *(const uint2*)(h0bT + base_ + t0m * H + t0j);               \
    if (tid < 576) {                                                   \
      sf1 = *(const uint2*)(h0fT + base_ + t1m * H + t1j);             \
      sb1 = *(const uint2*)(h0bT + base_ + t1m * H + t1j);             \
    }                                                                  \
  }
#define XG_COMMIT(BUF)                                                 \
  {                                                                    \
    *(uint2*)&B_s[BUF][t0j >> 3][t0m][t0j & 7] = sf0;                  \
    int k0_ = 100 + t0j;                                               \
    *(uint2*)&B_s[BUF][k0_ >> 3][t0m][k0_ & 7] = sb0;                  \
    if (tid < 576) {                                                   \
      *(uint2*)&B_s[BUF][t1j >> 3][t1m][t1j & 7] = sf1;                \
      int k1_ = 100 + t1j;                                             \
      *(uint2*)&B_s[BUF][k1_ >> 3][t1m][k1_ & 7] = sb1;                \
    }                                                                  \
  }

  const int g0 = blockIdx.x;
  XG_ISSUE(g0);
  XG_COMMIT(0);
  __syncthreads();

  for (int i = 0; i < NGRP; ++i) {
    if (i < NGRP - 1) XG_ISSUE(g0 + GSTRIDE * (i + 1));  // issue early
    const short(*Bb)[64][8] = B_s[i & 1];
    const int r0 = (g0 + GSTRIDE * i) * 64;
#pragma unroll
    for (int rg = 0; rg < 4; ++rg) {
      f32x4 accA = (f32x4){0.f, 0.f, 0.f, 0.f};
      f32x4 accB = (f32x4){0.f, 0.f, 0.f, 0.f};
#pragma unroll
      for (int kt = 0; kt < 7; ++kt) {
        bf16x8 hf = *(const bf16x8*)Bb[kt * 4 + q][rg * 16 + l16];
        accA = __builtin_amdgcn_mfma_f32_16x16x32_bf16(wfA[kt], hf, accA, 0, 0, 0);
        if (bvalid)
          accB = __builtin_amdgcn_mfma_f32_16x16x32_bf16(wfB[kt], hf, accB, 0, 0, 0);
      }
      const size_t row = (size_t)(r0 + rg * 16 + l16);
      {
        __half2 h01 = __floats2half2_rn(accA[0], accA[1]);
        __half2 h23 = __floats2half2_rn(accA[2], accA[3]);
        uint2 st; *(__half2*)&st.x = h01; *(__half2*)&st.y = h23;
        *(uint2*)(xg + row * G + 4 * jA) = st;
      }
      if (bvalid) {
        __half2 h01 = __floats2half2_rn(accB[0], accB[1]);
        __half2 h23 = __floats2half2_rn(accB[2], accB[3]);
        uint2 st; *(__half2*)&st.x = h01; *(__half2*)&st.y = h23;
        *(uint2*)(xg + row * G + 4 * jB) = st;
      }
    }
    if (i < NGRP - 1) XG_COMMIT((i & 1) ^ 1);  // commit late, other buffer
    __syncthreads();
  }
#undef XG_ISSUE
#undef XG_COMMIT
}

// ---- layer 1: MB1=4, 256 blocks, dense 4 tiles/wave (waves 0..6 busy) ------
__global__ __launch_bounds__(1024, 1) void lstm_l1(
    const unsigned short* __restrict__ h0fT, const unsigned short* __restrict__ h0bT,
    const unsigned short* __restrict__ pk_hh, const unsigned short* __restrict__ pk1b,
    const __half* __restrict__ xg,
    const float* __restrict__ fc_w, const float* __restrict__ fc_b,
    float* __restrict__ out) {
  __shared__ __align__(16) short A_s[2][16][16][8];      // h1, K=128
  __shared__ __align__(16) short A2_s[28][16][8];        // epilogue [h0|1] K=224
  __shared__ float hf_s[MB1][H];
  __shared__ float hb_s[MB1][H];
  __shared__ float fcw_s[3 * D1];
  __shared__ float fcb_s[3];
  __shared__ float logit_s[MB1][3];

  const int tid = threadIdx.x;
  const int lane = tid & 63, w = tid >> 6;   // 16 waves
  const int q = lane >> 4, l16 = lane & 15;
  const int b0 = blockIdx.x * MB1;           // 256 blocks
  const uint2* xg2 = (const uint2*)xg;       // 100 uint2 per (t,b) row

  for (int i = tid; i < 2 * 16 * 16 * 8; i += 1024) ((short*)A_s)[i] = 0;
  for (int i = tid; i < 25 * 16 * 8; i += 1024) ((short*)A2_s)[i] = 0;  // kg 0..24
  for (int i = tid; i < 3 * 16 * 8; i += 1024) {  // A2 kg25..27 zero + bias-one
    int jj = i & 7, gl = i >> 7;
    ((short*)&A2_s[25][0][0])[i] = (short)((gl == 0 && jj == 0) ? f2bf(1.f) : 0);
  }
  for (int i = tid; i < 3 * D1; i += 1024) fcw_s[i] = fc_w[i];
  if (tid < 3) fcb_s[tid] = fc_b[tid];

  const bool busy = (w < 7);                 // waves 0..6 own tiles 4w..4w+3
  const int m = l16 & 3, g16 = l16 >> 2;
  const int myMt = w * 4 + g16;
  const int jme = myMt * 4 + q;              // my element's j (>=100 invalid)
  const bool evalid = busy && (myMt < NT);
  int mts[4]; bool tv[4];
  bf16x8 wf[4][4];
  if (busy) {
#pragma unroll
    for (int i = 0; i < 4; ++i) {
      int mt = w * 4 + i; mts[i] = mt; tv[i] = (mt < NT);
#pragma unroll
      for (int kt = 0; kt < 4; ++kt)
        wf[i][kt] = *(const bf16x8*)(pk_hh + ((size_t)(kt * 4 + q) * NP + mt * 16 + l16) * 8);
    }
  }
  float c = 0.f;
  // per-lane own-element xg, running pointer (+102400 uint2 per t);
  // invalid jme (<=111) reads <=96B past the row — lands in ws, unused.
  const uint2* xgp = xg2 + (size_t)(b0 + m) * 100 + jme;
  uint2 xgCur = {0, 0};
  if (busy) { xgCur = *xgp; xgp += Bsz * 100; }
  __syncthreads();

  int p = 0;
  for (int t = 0; t < Tt; ++t) {
    if (busy) {
      uint2 xgNxt = xgCur;
      if (t < Tt - 1) { xgNxt = *xgp; xgp += Bsz * 100; }
      bf16x8 hfrag[4];
      // [l16] read: cols 4..15 hold write-time duplicates of rows 0..3.
#pragma unroll
      for (int kt = 0; kt < 4; ++kt) hfrag[kt] = *(const bf16x8*)A_s[p][kt * 4 + q][l16];
      f32x4 acc[4];
#pragma unroll
      for (int i = 0; i < 4; ++i) {
        acc[i] = (f32x4){0.f, 0.f, 0.f, 0.f};
        if (!tv[i]) continue;
#pragma unroll
        for (int kt = 0; kt < 4; ++kt)
          acc[i] = __builtin_amdgcn_mfma_f32_16x16x32_bf16(wf[i][kt], hfrag[kt], acc[i], 0, 0, 0);
      }
      float2 x01 = __half22float2(*(const __half2*)&xgCur.x);
      float2 x23 = __half22float2(*(const __half2*)&xgCur.y);
      float xr[4] = {x01.x, x01.y, x23.x, x23.y};
      float gr[4];
#pragma unroll
      for (int r = 0; r < 4; ++r) {
        float lo = (g16 & 1) ? acc[1][r] : acc[0][r];
        float hi = (g16 & 1) ? acc[3][r] : acc[2][r];
        gr[r] = ((g16 & 2) ? hi : lo) + xr[r];
      }
      float cc = sigm(gr[1]) * c + sigm(gr[0]) * tanhf_(gr[2]);
      c = cc;
      float h = sigm(gr[3]) * tanhf_(cc);
      if (evalid) {  // write-dup into all 4 mirror columns
        short hh = (short)f2bf(h);
        A_s[1 - p][jme >> 3][m][jme & 7] = hh;
        A_s[1 - p][jme >> 3][m + 4][jme & 7] = hh;
        A_s[1 - p][jme >> 3][m + 8][jme & 7] = hh;
        A_s[1 - p][jme >> 3][m + 12][jme & 7] = hh;
        if (t == Tt - 1) hf_s[m][jme] = h;
      }
      xgCur = xgNxt;
    }
    __syncthreads();
    p ^= 1;
  }

  // ---- layer-1 backward single step at t=T-1 (h=c=0) ----
  {
    const size_t base = ((size_t)(Tt - 1) * Bsz + b0) * H;
    if (tid < 100) {  // stage rows m=0..3 only (this block's batch)
      int m2 = tid / 25, j0 = (tid - (tid / 25) * 25) * 4;
      *(uint2*)&A2_s[j0 >> 3][m2][j0 & 7] = *(const uint2*)(h0fT + base + m2 * H + j0);
      int k = 100 + j0;
      *(uint2*)&A2_s[k >> 3][m2][k & 7] = *(const uint2*)(h0bT + base + m2 * H + j0);
    }
  }
  __syncthreads();
  if (busy) {
    f32x4 acc[4];
#pragma unroll
    for (int i = 0; i < 4; ++i) acc[i] = (f32x4){0.f, 0.f, 0.f, 0.f};
#pragma unroll
    for (int kt = 0; kt < 7; ++kt) {
      bf16x8 hf = *(const bf16x8*)A2_s[kt * 4 + q][l16 & 3];  // one-shot dup-read
#pragma unroll
      for (int i = 0; i < 4; ++i) {
        if (!tv[i]) continue;
        bf16x8 wfb = *(const bf16x8*)(pk1b + ((size_t)(kt * 4 + q) * NP + mts[i] * 16 + l16) * 8);
        acc[i] = __builtin_amdgcn_mfma_f32_16x16x32_bf16(wfb, hf, acc[i], 0, 0, 0);
      }
    }
    float gr[4];
#pragma unroll
    for (int r = 0; r < 4; ++r) {
      float lo = (g16 & 1) ? acc[1][r] : acc[0][r];
      float hi = (g16 & 1) ? acc[3][r] : acc[2][r];
      gr[r] = (g16 & 2) ? hi : lo;
    }
    float cc = sigm(gr[0]) * tanhf_(gr[2]);   // c_prev = 0
    if (evalid) hb_s[m][jme] = sigm(gr[3]) * tanhf_(cc);
  }
  __syncthreads();

  // ---- FC (3x200) + softmax ----
  if (tid < MB1 * 3) {
    int mr = tid / 3, cls = tid - mr * 3;
    float s = fcb_s[cls];
    for (int jj = 0; jj < H; ++jj) s += fcw_s[cls * D1 + jj] * hf_s[mr][jj];
    for (int jj = 0; jj < H; ++jj) s += fcw_s[cls * D1 + H + jj] * hb_s[mr][jj];
    logit_s[mr][cls] = s;
  }
  __syncthreads();
  if (tid < MB1) {
    float a = logit_s[tid][0], b = logit_s[tid][1], cc = logit_s[tid][2];
    float mx = fmaxf(a, fmaxf(b, cc));
    float e0 = __expf(a - mx), e1 = __expf(b - mx), e2 = __expf(cc - mx);
    float inv = 1.f / (e0 + e1 + e2);
    out[(b0 + tid) * 3 + 0] = e0 * inv;
    out[(b0 + tid) * 3 + 1] = e1 * inv;
    out[(b0 + tid) * 3 + 2] = e2 * inv;
  }
}

extern "C" void kernel_launch(void* const* d_in, const int* in_sizes, int n_in,
                              void* d_out, int out_size, void* d_ws, size_t ws_size,
                              hipStream_t stream) {
  const float* x        = (const float*)d_in[0];
  const float* w_ih_l0f = (const float*)d_in[1];
  const float* w_hh_l0f = (const float*)d_in[2];
  const float* b_ih_l0f = (const float*)d_in[3];
  const float* b_hh_l0f = (const float*)d_in[4];
  const float* w_ih_l0b = (const float*)d_in[5];
  const float* w_hh_l0b = (const float*)d_in[6];
  const float* b_ih_l0b = (const float*)d_in[7];
  const float* b_hh_l0b = (const float*)d_in[8];
  const float* w_ih_l1f = (const float*)d_in[9];
  const float* w_hh_l1f = (const float*)d_in[10];
  const float* b_ih_l1f = (const float*)d_in[11];
  const float* b_hh_l1f = (const float*)d_in[12];
  const float* w_ih_l1b = (const float*)d_in[13];
  // d_in[14] = w_hh_l1b unused (reverse dir at t=T-1 has h=0)
  const float* b_ih_l1b = (const float*)d_in[15];
  const float* b_hh_l1b = (const float*)d_in[16];
  const float* fc_w     = (const float*)d_in[17];
  const float* fc_b     = (const float*)d_in[18];

  unsigned short* h0fT = (unsigned short*)d_ws;
  unsigned short* h0bT = h0fT + (size_t)Tt * Bsz * H;
  __half* xgT          = (__half*)(h0bT + (size_t)Tt * Bsz * H);
  unsigned short* pk0f = (unsigned short*)(xgT + (size_t)Tt * Bsz * G);
  unsigned short* pk0b = pk0f + 16 * NP * 8;
  unsigned short* pkhh = pk0b + 16 * NP * 8;
  unsigned short* pkxg = pkhh + 16 * NP * 8;
  unsigned short* pk1b = pkxg + 28 * NP * 8;

  pack_all<<<dim3(448, 5), 256, 0, stream>>>(
      w_hh_l0f, w_ih_l0f, b_ih_l0f, b_hh_l0f,
      w_hh_l0b, w_ih_l0b, b_ih_l0b, b_hh_l0b,
      w_hh_l1f, b_ih_l1f, b_hh_l1f,
      w_ih_l1f, w_ih_l1b, b_ih_l1b, b_hh_l1b,
      pk0f, pk0b, pkhh, pkxg, pk1b);

  lstm_l0<<<dim3(Bsz / MB, 2), 1024, 0, stream>>>(x, pk0f, pk0b, h0fT, h0bT);
  gemm_xg<<<GSTRIDE, 1024, 0, stream>>>(h0fT, h0bT, pkxg, xgT);
  lstm_l1<<<Bsz / MB1, 1024, 0, stream>>>(h0fT, h0bT, pkhh, pk1b, xgT,
                                          fc_w, fc_b, (float*)d_out);
}

// Round 4
// 357.492 us; speedup vs baseline: 1.3238x; 1.0025x over previous
//
#include <hip/hip_runtime.h>
#include <hip/hip_fp16.h>

// LSTM_48850958024796 — R20: dense-wave l0. R19 counters showed l0 stuck at
// ~141us with conflicts OFF the critical path; analysis: all 16 waves read
// IDENTICAL hfrag (no w in the address) -> 64 ds_read_b128/step/CU (~770cy
// LDS pipe convoy) for 4KB unique data, while 7 waves carry 1 tile only.
// Port l1's dense layout: waves 0..6 own 4 tiles each (16 MFMA/step), lane
// halves lo/hi consume acc0/1 vs acc2/3 (cols are write-dup copies), 2 LSTM
// cells per lane. h-store -> waves 7..10, x-prefetch -> wave 11 (global
// latency off the MFMA waves). Per-CU-step: LDS b128 reads 64->28, MFMA
// 100->112, gate lanes 1024->896.
// Falsified levers (do not retry): barrier_nv (neutral), unroll-2 (neg),
// mega-kernel+grid.sync (724), wave specialization one-kernel (spill, 877),
// small-MB block-split (R17, 473: 2x MFMA work), dup-READ b128 (R18, no
// broadcast -> 4x conflicts).
// Scan math (R3-proven): gates^T = W(A) @ [h|x|1]^T(B), cols gate-interleaved
// (n'=4j+gate). l0: MB=8 write-dup cols 8..15. l1: MB1=4, dense 4 tiles/wave.

typedef __attribute__((ext_vector_type(8))) short bf16x8;
typedef __attribute__((ext_vector_type(4))) float f32x4;

constexpr int Bsz = 1024, Tt = 128, IN_ = 5, H = 100, G = 400, D1 = 200;
constexpr int NP = 512;   // packed gate cols (32 tiles of 16)
constexpr int NT = 25;    // real tiles (400/16)
constexpr int MB = 8;     // batch rows per block (l0)
constexpr int MB1 = 4;    // batch rows per block (l1)
constexpr int NGRP = 4;   // row-groups per gemm_xg block
constexpr int GSTRIDE = 512;  // gemm_xg grid size

__device__ __forceinline__ float sigm(float x)   { return 1.f / (1.f + __expf(-x)); }
__device__ __forceinline__ float tanhf_(float x) { return 1.f - 2.f / (__expf(2.f * x) + 1.f); }
__device__ __forceinline__ unsigned short f2bf(float f) {
  unsigned u = __float_as_uint(f);
  u += 0x7fff + ((u >> 16) & 1);
  return (unsigned short)(u >> 16);
}

// packed col n' (0..511): j=n'>>2, gate=n'&3, src row n = gate*100+j; j>=100->0
__device__ __forceinline__ void pack_body(
    const float* wA, int KA, const float* wB, int KB, int kbo,
    const float* b1, const float* b2, int bias_k,
    unsigned short* dst, int Kg, int idx) {
  if (idx >= Kg * NP * 8) return;
  int jj = idx & 7, rest = idx >> 3;
  int np_ = rest % NP, g = rest / NP;
  int j = np_ >> 2, gate = np_ & 3;
  int k = g * 8 + jj;
  float v = 0.f;
  if (j < H) {
    int n = gate * H + j;
    if (k < KA) v = wA[n * KA + k];
    else if (KB > 0 && k >= kbo && k < kbo + KB) v = wB[n * KB + (k - kbo)];
    else if (k == bias_k) v = b1[n] + b2[n];
  }
  dst[idx] = f2bf(v);
}

__global__ void pack_all(
    const float* __restrict__ w_hh_l0f, const float* __restrict__ w_ih_l0f,
    const float* __restrict__ b_ih_l0f, const float* __restrict__ b_hh_l0f,
    const float* __restrict__ w_hh_l0b, const float* __restrict__ w_ih_l0b,
    const float* __restrict__ b_ih_l0b, const float* __restrict__ b_hh_l0b,
    const float* __restrict__ w_hh_l1f, const float* __restrict__ b_ih_l1f,
    const float* __restrict__ b_hh_l1f,
    const float* __restrict__ w_ih_l1f, const float* __restrict__ w_ih_l1b,
    const float* __restrict__ b_ih_l1b, const float* __restrict__ b_hh_l1b,
    unsigned short* __restrict__ pk0f, unsigned short* __restrict__ pk0b,
    unsigned short* __restrict__ pkhh, unsigned short* __restrict__ pkxg,
    unsigned short* __restrict__ pk1b) {
  int idx = blockIdx.x * 256 + threadIdx.x;
  switch (blockIdx.y) {
    case 0: pack_body(w_hh_l0f, 100, w_ih_l0f, 5, 100, b_ih_l0f, b_hh_l0f, 105, pk0f, 16, idx); break;
    case 1: pack_body(w_hh_l0b, 100, w_ih_l0b, 5, 100, b_ih_l0b, b_hh_l0b, 105, pk0b, 16, idx); break;
    case 2: pack_body(w_hh_l1f, 100, nullptr, 0, 0, b_ih_l1f, b_hh_l1f, -1, pkhh, 16, idx); break;
    case 3: pack_body(w_ih_l1f, 200, nullptr, 0, 0, b_ih_l1f, b_hh_l1f, 200, pkxg, 28, idx); break;
    default: pack_body(w_ih_l1b, 200, nullptr, 0, 0, b_ih_l1b, b_hh_l1b, 200, pk1b, 28, idx);
  }
}

// ------------- layer 0 scan (grid = 128 x 2 dirs, 1024 thr) -----------------
// Dense: waves 0..6 own tiles 4w..4w+3; lo lanes (l16<8) -> acc0/1, hi lanes
// -> acc2/3; 2 cells/lane. Waves 7..10 store h, wave 11 prefetches x.
__global__ __launch_bounds__(1024, 1) void lstm_l0(
    const float* __restrict__ x,
    const unsigned short* __restrict__ pk_f, const unsigned short* __restrict__ pk_b,
    unsigned short* __restrict__ h0fT, unsigned short* __restrict__ h0bT) {
  __shared__ __align__(16) short A_s[2][16][16][8];  // [buf][kg][m16][jj], K=128

  const int tid = threadIdx.x;
  const int lane = tid & 63, w = tid >> 6;       // 16 waves
  const int q = lane >> 4, l16 = lane & 15;
  const int b0 = blockIdx.x * MB;
  const int dir = blockIdx.y;
  const unsigned short* pk = dir ? pk_b : pk_f;
  unsigned short* hT = dir ? h0bT : h0fT;

  for (int i = tid; i < 2 * 16 * 16 * 8; i += 1024) ((short*)A_s)[i] = 0;

  const bool busy = (w < 7);                 // waves 0..6 own tiles 4w..4w+3
  const bool hi = (l16 >= 8);
  const int row = l16 & 7;
  bf16x8 wf[4][4];
  if (busy) {
#pragma unroll
    for (int i = 0; i < 4; ++i) {
      int mt = w * 4 + i;                    // mt<32; pk zero-padded j>=100
#pragma unroll
      for (int kt = 0; kt < 4; ++kt)
        wf[i][kt] = *(const bf16x8*)(pk + ((size_t)(kt * 4 + q) * NP + mt * 16 + l16) * 8);
    }
  }
  // my two cells: tiles mt0, mt0+1 (lo: 4w,4w+1; hi: 4w+2,4w+3)
  const int mt0 = w * 4 + (hi ? 2 : 0);
  const int j0 = mt0 * 4 + q, j1 = j0 + 4;
  const bool v0 = busy && (mt0 < NT);
  const bool v1 = busy && (mt0 + 1 < NT);
  float c0 = 0.f, c1 = 0.f;

  // h-store lanes: waves 7..10 (st<200); x lanes: wave 11 (xt<40)
  const int st = tid - 448;
  const bool sl = (st >= 0 && st < 200);
  const int sm = sl ? st / 25 : 0, sj = sl ? (st - (st / 25) * 25) * 4 : 0;
  const int xt = tid - 704;
  const bool xl = (xt >= 0 && xt < MB * IN_);
  const int xm = xl ? xt / IN_ : 0;
  const int xe = xl ? xt - xm * IN_ : 0;
  const float* xp = x + ((size_t)(b0 + xm) * Tt + (dir ? Tt - 2 : 1)) * IN_ + xe;
  const int xstride = dir ? -IN_ : IN_;
  unsigned short* hp =
      hT + ((size_t)(dir ? Tt - 1 : 0) * Bsz + b0 + sm) * H + sj;
  const int hstride = dir ? -(Bsz * H) : (Bsz * H);
  __syncthreads();
  if (tid < 16) {  // bias-one col k=105 (kg13,jj1), both bufs, all 16 cols
    A_s[0][13][tid][1] = (short)f2bf(1.f);
    A_s[1][13][tid][1] = (short)f2bf(1.f);
  }
  if (xl) {  // x(t_first) -> buf0, direct f32 read, write-dup
    int t0 = dir ? (Tt - 1) : 0;
    int k = 100 + xe;
    short xv = (short)f2bf(x[((size_t)(b0 + xm) * Tt + t0) * IN_ + xe]);
    A_s[0][k >> 3][xm][k & 7] = xv;
    A_s[0][k >> 3][xm + 8][k & 7] = xv;
  }
  __syncthreads();

  int p = 0;
  for (int step = 0; step < Tt; ++step) {
    if (step > 0 && sl) {  // coalesced store of h(prev), idle waves 7..10
      uint2 hv = *(const uint2*)&A_s[p][sj >> 3][sm][sj & 7];
      *(uint2*)hp = hv;
      hp += hstride;
    }
    float xn = 0.f;
    const bool do_x = xl && (step < Tt - 1);
    if (do_x) { xn = *xp; xp += xstride; }
    if (busy) {
      f32x4 acc0 = (f32x4){0.f, 0.f, 0.f, 0.f};
      f32x4 acc1 = (f32x4){0.f, 0.f, 0.f, 0.f};
      f32x4 acc2 = (f32x4){0.f, 0.f, 0.f, 0.f};
      f32x4 acc3 = (f32x4){0.f, 0.f, 0.f, 0.f};
#pragma unroll
      for (int kt = 0; kt < 4; ++kt) {
        bf16x8 hf = *(const bf16x8*)A_s[p][kt * 4 + q][l16];
        acc0 = __builtin_amdgcn_mfma_f32_16x16x32_bf16(wf[0][kt], hf, acc0, 0, 0, 0);
        acc1 = __builtin_amdgcn_mfma_f32_16x16x32_bf16(wf[1][kt], hf, acc1, 0, 0, 0);
        acc2 = __builtin_amdgcn_mfma_f32_16x16x32_bf16(wf[2][kt], hf, acc2, 0, 0, 0);
        acc3 = __builtin_amdgcn_mfma_f32_16x16x32_bf16(wf[3][kt], hf, acc3, 0, 0, 0);
      }
      // compile-time-indexed selects (no runtime acc indexing -> no scratch)
      float gA0 = hi ? acc2[0] : acc0[0], gA1 = hi ? acc2[1] : acc0[1];
      float gA2 = hi ? acc2[2] : acc0[2], gA3 = hi ? acc2[3] : acc0[3];
      float gB0 = hi ? acc3[0] : acc1[0], gB1 = hi ? acc3[1] : acc1[1];
      float gB2 = hi ? acc3[2] : acc1[2], gB3 = hi ? acc3[3] : acc1[3];
      float cc0 = sigm(gA1) * c0 + sigm(gA0) * tanhf_(gA2);
      c0 = cc0;
      float h0v = sigm(gA3) * tanhf_(cc0);
      float cc1 = sigm(gB1) * c1 + sigm(gB0) * tanhf_(gB2);
      c1 = cc1;
      float h1v = sigm(gB3) * tanhf_(cc1);
      if (v0) {
        short hh = (short)f2bf(h0v);
        A_s[1 - p][j0 >> 3][row][j0 & 7] = hh;
        A_s[1 - p][j0 >> 3][row + 8][j0 & 7] = hh;
      }
      if (v1) {
        short hh = (short)f2bf(h1v);
        A_s[1 - p][j1 >> 3][row][j1 & 7] = hh;
        A_s[1 - p][j1 >> 3][row + 8][j1 & 7] = hh;
      }
    }
    if (do_x) {
      int k = 100 + xe;
      short xv = (short)f2bf(xn);
      A_s[1 - p][k >> 3][xm][k & 7] = xv;
      A_s[1 - p][k >> 3][xm + 8][k & 7] = xv;
    }
    __syncthreads();
    p ^= 1;
  }
  if (sl) *(uint2*)hp = *(const uint2*)&A_s[p][sj >> 3][sm][sj & 7];  // final h
}

// ---- xgT[t*1024+b][400] = [h0f|h0b] @ W_ih_l1f^T + bias (fp16, interleaved) --
// 512 resident blocks x NGRP=4 row-groups, double-buffered LDS, async stage.
__global__ __launch_bounds__(1024, 1) void gemm_xg(
    const unsigned short* __restrict__ h0fT, const unsigned short* __restrict__ h0bT,
    const unsigned short* __restrict__ pkw, __half* __restrict__ xg) {
  __shared__ __align__(16) short B_s[2][28][64][8];  // K=224 aug (k=200 bias-one)
  const int tid = threadIdx.x;
  const int lane = tid & 63, w = tid >> 6;   // 16 waves
  const int q = lane >> 4, l16 = lane & 15;

  // static init: kg 25..27 both buffers (zero + bias-one at k=200, jj=0)
#pragma unroll
  for (int b = 0; b < 2; ++b)
    for (int i = tid; i < 3 * 64 * 8; i += 1024) {
      int jj = i & 7, gl = i >> 9;
      ((short*)&B_s[b][25][0][0])[i] = (short)((gl == 0 && jj == 0) ? f2bf(1.f) : 0);
    }

  const int mtA = w, mtB = w + 16;
  const bool bvalid = (mtB < NT);
  bf16x8 wfA[7], wfB[7];
#pragma unroll
  for (int kt = 0; kt < 7; ++kt) {
    wfA[kt] = *(const bf16x8*)(pkw + ((size_t)(kt * 4 + q) * NP + mtA * 16 + l16) * 8);
    wfB[kt] = *(const bf16x8*)(pkw + ((size_t)(kt * 4 + q) * NP + mtB * 16 + l16) * 8);
  }
  const int jA = mtA * 4 + q, jB = mtB * 4 + q;

  // staging tasks: idx -> (m=idx/25, j0=(idx%25)*4); tid owns idx=tid and
  // (tid<576) idx=tid+1024. 1600 tasks stage 64 rows x [h0f|h0b].
  const int t0m = tid / 25, t0j = (tid - t0m * 25) * 4;
  const int t1 = tid + 1024;
  const int t1m = t1 / 25, t1j = (t1 - t1m * 25) * 4;
  uint2 sf0, sb0, sf1, sb1;

#define XG_ISSUE(GRP)                                                  \
  {                                                                    \
    size_t base_ = (size_t)(GRP)*64 * H;                               \
    sf0 = *(const uint2*)(h0fT + base_ + t0m * H + t0j);               \
    sb0 = *(const uint2*)(h0bT + base_ + t0m * H + t0j);               \
    if (tid < 576) {                                                   \
      sf1 = *(const uint2*)(h0fT + base_ + t1m * H + t1j);             \
      sb1 = *(const uint2*)(h0bT + base_ + t1m * H + t1j);             \
    }                                                                  \
  }
#define XG_COMMIT(BUF)                                                 \
  {                                                                    \
    *(uint2*)&B_s[BUF][t0j >> 3][t0m][t0j & 7] = sf0;                  \
    int k0_ = 100 + t0j;                                               \
    *(uint2*)&B_s[BUF][k0_ >> 3][t0m][k0_ & 7] = sb0;                  \
    if (tid < 576) {                                                   \
      *(uint2*)&B_s[BUF][t1j >> 3][t1m][t1j & 7] = sf1;                \
      int k1_ = 100 + t1j;                                             \
      *(uint2*)&B_s[BUF][k1_ >> 3][t1m][k1_ & 7] = sb1;                \
    }                                                                  \
  }

  const int g0 = blockIdx.x;
  XG_ISSUE(g0);
  XG_COMMIT(0);
  __syncthreads();

  for (int i = 0; i < NGRP; ++i) {
    if (i < NGRP - 1) XG_ISSUE(g0 + GSTRIDE * (i + 1));  // issue early
    const short(*Bb)[64][8] = B_s[i & 1];
    const int r0 = (g0 + GSTRIDE * i) * 64;
#pragma unroll
    for (int rg = 0; rg < 4; ++rg) {
      f32x4 accA = (f32x4){0.f, 0.f, 0.f, 0.f};
      f32x4 accB = (f32x4){0.f, 0.f, 0.f, 0.f};
#pragma unroll
      for (int kt = 0; kt < 7; ++kt) {
        bf16x8 hf = *(const bf16x8*)Bb[kt * 4 + q][rg * 16 + l16];
        accA = __builtin_amdgcn_mfma_f32_16x16x32_bf16(wfA[kt], hf, accA, 0, 0, 0);
        if (bvalid)
          accB = __builtin_amdgcn_mfma_f32_16x16x32_bf16(wfB[kt], hf, accB, 0, 0, 0);
      }
      const size_t row = (size_t)(r0 + rg * 16 + l16);
      {
        __half2 h01 = __floats2half2_rn(accA[0], accA[1]);
        __half2 h23 = __floats2half2_rn(accA[2], accA[3]);
        uint2 st; *(__half2*)&st.x = h01; *(__half2*)&st.y = h23;
        *(uint2*)(xg + row * G + 4 * jA) = st;
      }
      if (bvalid) {
        __half2 h01 = __floats2half2_rn(accB[0], accB[1]);
        __half2 h23 = __floats2half2_rn(accB[2], accB[3]);
        uint2 st; *(__half2*)&st.x = h01; *(__half2*)&st.y = h23;
        *(uint2*)(xg + row * G + 4 * jB) = st;
      }
    }
    if (i < NGRP - 1) XG_COMMIT((i & 1) ^ 1);  // commit late, other buffer
    __syncthreads();
  }
#undef XG_ISSUE
#undef XG_COMMIT
}

// ---- layer 1: MB1=4, 256 blocks, dense 4 tiles/wave (waves 0..6 busy) ------
__global__ __launch_bounds__(1024, 1) void lstm_l1(
    const unsigned short* __restrict__ h0fT, const unsigned short* __restrict__ h0bT,
    const unsigned short* __restrict__ pk_hh, const unsigned short* __restrict__ pk1b,
    const __half* __restrict__ xg,
    const float* __restrict__ fc_w, const float* __restrict__ fc_b,
    float* __restrict__ out) {
  __shared__ __align__(16) short A_s[2][16][16][8];      // h1, K=128
  __shared__ __align__(16) short A2_s[28][16][8];        // epilogue [h0|1] K=224
  __shared__ float hf_s[MB1][H];
  __shared__ float hb_s[MB1][H];
  __shared__ float fcw_s[3 * D1];
  __shared__ float fcb_s[3];
  __shared__ float logit_s[MB1][3];

  const int tid = threadIdx.x;
  const int lane = tid & 63, w = tid >> 6;   // 16 waves
  const int q = lane >> 4, l16 = lane & 15;
  const int b0 = blockIdx.x * MB1;           // 256 blocks
  const uint2* xg2 = (const uint2*)xg;       // 100 uint2 per (t,b) row

  for (int i = tid; i < 2 * 16 * 16 * 8; i += 1024) ((short*)A_s)[i] = 0;
  for (int i = tid; i < 25 * 16 * 8; i += 1024) ((short*)A2_s)[i] = 0;  // kg 0..24
  for (int i = tid; i < 3 * 16 * 8; i += 1024) {  // A2 kg25..27 zero + bias-one
    int jj = i & 7, gl = i >> 7;
    ((short*)&A2_s[25][0][0])[i] = (short)((gl == 0 && jj == 0) ? f2bf(1.f) : 0);
  }
  for (int i = tid; i < 3 * D1; i += 1024) fcw_s[i] = fc_w[i];
  if (tid < 3) fcb_s[tid] = fc_b[tid];

  const bool busy = (w < 7);                 // waves 0..6 own tiles 4w..4w+3
  const int m = l16 & 3, g16 = l16 >> 2;
  const int myMt = w * 4 + g16;
  const int jme = myMt * 4 + q;              // my element's j (>=100 invalid)
  const bool evalid = busy && (myMt < NT);
  int mts[4]; bool tv[4];
  bf16x8 wf[4][4];
  if (busy) {
#pragma unroll
    for (int i = 0; i < 4; ++i) {
      int mt = w * 4 + i; mts[i] = mt; tv[i] = (mt < NT);
#pragma unroll
      for (int kt = 0; kt < 4; ++kt)
        wf[i][kt] = *(const bf16x8*)(pk_hh + ((size_t)(kt * 4 + q) * NP + mt * 16 + l16) * 8);
    }
  }
  float c = 0.f;
  // per-lane own-element xg, running pointer (+102400 uint2 per t);
  // invalid jme (<=111) reads <=96B past the row — lands in ws, unused.
  const uint2* xgp = xg2 + (size_t)(b0 + m) * 100 + jme;
  uint2 xgCur = {0, 0};
  if (busy) { xgCur = *xgp; xgp += Bsz * 100; }
  __syncthreads();

  int p = 0;
  for (int t = 0; t < Tt; ++t) {
    if (busy) {
      uint2 xgNxt = xgCur;
      if (t < Tt - 1) { xgNxt = *xgp; xgp += Bsz * 100; }
      bf16x8 hfrag[4];
      // [l16] read: cols 4..15 hold write-time duplicates of rows 0..3.
#pragma unroll
      for (int kt = 0; kt < 4; ++kt) hfrag[kt] = *(const bf16x8*)A_s[p][kt * 4 + q][l16];
      f32x4 acc[4];
#pragma unroll
      for (int i = 0; i < 4; ++i) {
        acc[i] = (f32x4){0.f, 0.f, 0.f, 0.f};
        if (!tv[i]) continue;
#pragma unroll
        for (int kt = 0; kt < 4; ++kt)
          acc[i] = __builtin_amdgcn_mfma_f32_16x16x32_bf16(wf[i][kt], hfrag[kt], acc[i], 0, 0, 0);
      }
      float2 x01 = __half22float2(*(const __half2*)&xgCur.x);
      float2 x23 = __half22float2(*(const __half2*)&xgCur.y);
      float xr[4] = {x01.x, x01.y, x23.x, x23.y};
      float gr[4];
#pragma unroll
      for (int r = 0; r < 4; ++r) {
        float lo = (g16 & 1) ? acc[1][r] : acc[0][r];
        float hi = (g16 & 1) ? acc[3][r] : acc[2][r];
        gr[r] = ((g16 & 2) ? hi : lo) + xr[r];
      }
      float cc = sigm(gr[1]) * c + sigm(gr[0]) * tanhf_(gr[2]);
      c = cc;
      float h = sigm(gr[3]) * tanhf_(cc);
      if (evalid) {  // write-dup into all 4 mirror columns
        short hh = (short)f2bf(h);
        A_s[1 - p][jme >> 3][m][jme & 7] = hh;
        A_s[1 - p][jme >> 3][m + 4][jme & 7] = hh;
        A_s[1 - p][jme >> 3][m + 8][jme & 7] = hh;
        A_s[1 - p][jme >> 3][m + 12][jme & 7] = hh;
        if (t == Tt - 1) hf_s[m][jme] = h;
      }
      xgCur = xgNxt;
    }
    __syncthreads();
    p ^= 1;
  }

  // ---- layer-1 backward single step at t=T-1 (h=c=0) ----
  {
    const size_t base = ((size_t)(Tt - 1) * Bsz + b0) * H;
    if (tid < 100) {  // stage rows m=0..3 only (this block's batch)
      int m2 = tid / 25, j0 = (tid - (tid / 25) * 25) * 4;
      *(uint2*)&A2_s[j0 >> 3][m2][j0 & 7] = *(const uint2*)(h0fT + base + m2 * H + j0);
      int k = 100 + j0;
      *(uint2*)&A2_s[k >> 3][m2][k & 7] = *(const uint2*)(h0bT + base + m2 * H + j0);
    }
  }
  __syncthreads();
  if (busy) {
    f32x4 acc[4];
#pragma unroll
    for (int i = 0; i < 4; ++i) acc[i] = (f32x4){0.f, 0.f, 0.f, 0.f};
#pragma unroll
    for (int kt = 0; kt < 7; ++kt) {
      bf16x8 hf = *(const bf16x8*)A2_s[kt * 4 + q][l16 & 3];  // one-shot dup-read
#pragma unroll
      for (int i = 0; i < 4; ++i) {
        if (!tv[i]) continue;
        bf16x8 wfb = *(const bf16x8*)(pk1b + ((size_t)(kt * 4 + q) * NP + mts[i] * 16 + l16) * 8);
        acc[i] = __builtin_amdgcn_mfma_f32_16x16x32_bf16(wfb, hf, acc[i], 0, 0, 0);
      }
    }
    float gr[4];
#pragma unroll
    for (int r = 0; r < 4; ++r) {
      float lo = (g16 & 1) ? acc[1][r] : acc[0][r];
      float hi = (g16 & 1) ? acc[3][r] : acc[2][r];
      gr[r] = (g16 & 2) ? hi : lo;
    }
    float cc = sigm(gr[0]) * tanhf_(gr[2]);   // c_prev = 0
    if (evalid) hb_s[m][jme] = sigm(gr[3]) * tanhf_(cc);
  }
  __syncthreads();

  // ---- FC (3x200) + softmax ----
  if (tid < MB1 * 3) {
    int mr = tid / 3, cls = tid - mr * 3;
    float s = fcb_s[cls];
    for (int jj = 0; jj < H; ++jj) s += fcw_s[cls * D1 + jj] * hf_s[mr][jj];
    for (int jj = 0; jj < H; ++jj) s += fcw_s[cls * D1 + H + jj] * hb_s[mr][jj];
    logit_s[mr][cls] = s;
  }
  __syncthreads();
  if (tid < MB1) {
    float a = logit_s[tid][0], b = logit_s[tid][1], cc = logit_s[tid][2];
    float mx = fmaxf(a, fmaxf(b, cc));
    float e0 = __expf(a - mx), e1 = __expf(b - mx), e2 = __expf(cc - mx);
    float inv = 1.f / (e0 + e1 + e2);
    out[(b0 + tid) * 3 + 0] = e0 * inv;
    out[(b0 + tid) * 3 + 1] = e1 * inv;
    out[(b0 + tid) * 3 + 2] = e2 * inv;
  }
}

extern "C" void kernel_launch(void* const* d_in, const int* in_sizes, int n_in,
                              void* d_out, int out_size, void* d_ws, size_t ws_size,
                              hipStream_t stream) {
  const float* x        = (const float*)d_in[0];
  const float* w_ih_l0f = (const float*)d_in[1];
  const float* w_hh_l0f = (const float*)d_in[2];
  const float* b_ih_l0f = (const float*)d_in[3];
  const float* b_hh_l0f = (const float*)d_in[4];
  const float* w_ih_l0b = (const float*)d_in[5];
  const float* w_hh_l0b = (const float*)d_in[6];
  const float* b_ih_l0b = (const float*)d_in[7];
  const float* b_hh_l0b = (const float*)d_in[8];
  const float* w_ih_l1f = (const float*)d_in[9];
  const float* w_hh_l1f = (const float*)d_in[10];
  const float* b_ih_l1f = (const float*)d_in[11];
  const float* b_hh_l1f = (const float*)d_in[12];
  const float* w_ih_l1b = (const float*)d_in[13];
  // d_in[14] = w_hh_l1b unused (reverse dir at t=T-1 has h=0)
  const float* b_ih_l1b = (const float*)d_in[15];
  const float* b_hh_l1b = (const float*)d_in[16];
  const float* fc_w     = (const float*)d_in[17];
  const float* fc_b     = (const float*)d_in[18];

  unsigned short* h0fT = (unsigned short*)d_ws;
  unsigned short* h0bT = h0fT + (size_t)Tt * Bsz * H;
  __half* xgT          = (__half*)(h0bT + (size_t)Tt * Bsz * H);
  unsigned short* pk0f = (unsigned short*)(xgT + (size_t)Tt * Bsz * G);
  unsigned short* pk0b = pk0f + 16 * NP * 8;
  unsigned short* pkhh = pk0b + 16 * NP * 8;
  unsigned short* pkxg = pkhh + 16 * NP * 8;
  unsigned short* pk1b = pkxg + 28 * NP * 8;

  pack_all<<<dim3(448, 5), 256, 0, stream>>>(
      w_hh_l0f, w_ih_l0f, b_ih_l0f, b_hh_l0f,
      w_hh_l0b, w_ih_l0b, b_ih_l0b, b_hh_l0b,
      w_hh_l1f, b_ih_l1f, b_hh_l1f,
      w_ih_l1f, w_ih_l1b, b_ih_l1b, b_hh_l1b,
      pk0f, pk0b, pkhh, pkxg, pk1b);

  lstm_l0<<<dim3(Bsz / MB, 2), 1024, 0, stream>>>(x, pk0f, pk0b, h0fT, h0bT);
  gemm_xg<<<GSTRIDE, 1024, 0, stream>>>(h0fT, h0bT, pkxg, xgT);
  lstm_l1<<<Bsz / MB1, 1024, 0, stream>>>(h0fT, h0bT, pkhh, pk1b, xgT,
                                          fc_w, fc_b, (float*)d_out);
}

// Round 5
// 354.611 us; speedup vs baseline: 1.3345x; 1.0081x over previous
//
#include <hip/hip_runtime.h>
#include <hip/hip_fp16.h>

// LSTM_48850958024796 — R21: revert lstm_l0 to the exact R16 structure
// (134.0us measured — partner8 swizzle, 2 tiles/wave, 16 busy waves, stores
// on tid<200, x on tid<40). R18/R19/R20 issue-reduction attacks all landed
// 140-147us: l0 is latency/structure-bound at 1 block/CU (barrier + ds_read
// -> MFMA -> transcendental chain -> ds_write round trip), NOT issue-bound.
// Keep R19's gemm_xg (512 resident blocks, dbuf, async stage) and R19's l1
// (write-dup dense) — "rest" holds at ~211us with these.
// Falsified levers (do not retry): barrier_nv (2x neutral), unroll-2 (neg),
// mega-kernel+grid.sync (724), wave specialization one-kernel (spill, 877),
// small-MB block-split (R17, 473: 2x MFMA work), dup-READ b128 (R18, no
// b128 broadcast -> 4x conflicts), l0 write-dup (R19, 141), l0 dense waves +
// dedicated store/x waves (R20, 147), LDS-issue reduction in l0 (R19/R20
// neutral -> latency-bound).
// Scan math (R3-proven): gates^T = W(A) @ [h|x|1]^T(B), cols gate-interleaved
// (n'=4j+gate). l0: MB=8, 2 tiles/wave, spread via ds_swizzle(0x17).
// l1: MB1=4, 256 blocks, dense 4 tiles/wave (waves 0..6), write-dup cols.

typedef __attribute__((ext_vector_type(8))) short bf16x8;
typedef __attribute__((ext_vector_type(4))) float f32x4;

constexpr int Bsz = 1024, Tt = 128, IN_ = 5, H = 100, G = 400, D1 = 200;
constexpr int NP = 512;   // packed gate cols (32 tiles of 16)
constexpr int NT = 25;    // real tiles (400/16)
constexpr int MB = 8;     // batch rows per block (l0)
constexpr int MB1 = 4;    // batch rows per block (l1)
constexpr int NGRP = 4;   // row-groups per gemm_xg block
constexpr int GSTRIDE = 512;  // gemm_xg grid size

__device__ __forceinline__ float sigm(float x)   { return 1.f / (1.f + __expf(-x)); }
__device__ __forceinline__ float tanhf_(float x) { return 1.f - 2.f / (__expf(2.f * x) + 1.f); }
__device__ __forceinline__ unsigned short f2bf(float f) {
  unsigned u = __float_as_uint(f);
  u += 0x7fff + ((u >> 16) & 1);
  return (unsigned short)(u >> 16);
}
// src lane = lane & ~8 (keeps bits 0,1,2,4): MB=8 2-way spread
__device__ __forceinline__ float partner8(float v) {
  return __uint_as_float(
      (unsigned)__builtin_amdgcn_ds_swizzle((int)__float_as_uint(v), 0x17));
}

// packed col n' (0..511): j=n'>>2, gate=n'&3, src row n = gate*100+j; j>=100->0
__device__ __forceinline__ void pack_body(
    const float* wA, int KA, const float* wB, int KB, int kbo,
    const float* b1, const float* b2, int bias_k,
    unsigned short* dst, int Kg, int idx) {
  if (idx >= Kg * NP * 8) return;
  int jj = idx & 7, rest = idx >> 3;
  int np_ = rest % NP, g = rest / NP;
  int j = np_ >> 2, gate = np_ & 3;
  int k = g * 8 + jj;
  float v = 0.f;
  if (j < H) {
    int n = gate * H + j;
    if (k < KA) v = wA[n * KA + k];
    else if (KB > 0 && k >= kbo && k < kbo + KB) v = wB[n * KB + (k - kbo)];
    else if (k == bias_k) v = b1[n] + b2[n];
  }
  dst[idx] = f2bf(v);
}

__global__ void pack_all(
    const float* __restrict__ w_hh_l0f, const float* __restrict__ w_ih_l0f,
    const float* __restrict__ b_ih_l0f, const float* __restrict__ b_hh_l0f,
    const float* __restrict__ w_hh_l0b, const float* __restrict__ w_ih_l0b,
    const float* __restrict__ b_ih_l0b, const float* __restrict__ b_hh_l0b,
    const float* __restrict__ w_hh_l1f, const float* __restrict__ b_ih_l1f,
    const float* __restrict__ b_hh_l1f,
    const float* __restrict__ w_ih_l1f, const float* __restrict__ w_ih_l1b,
    const float* __restrict__ b_ih_l1b, const float* __restrict__ b_hh_l1b,
    unsigned short* __restrict__ pk0f, unsigned short* __restrict__ pk0b,
    unsigned short* __restrict__ pkhh, unsigned short* __restrict__ pkxg,
    unsigned short* __restrict__ pk1b) {
  int idx = blockIdx.x * 256 + threadIdx.x;
  switch (blockIdx.y) {
    case 0: pack_body(w_hh_l0f, 100, w_ih_l0f, 5, 100, b_ih_l0f, b_hh_l0f, 105, pk0f, 16, idx); break;
    case 1: pack_body(w_hh_l0b, 100, w_ih_l0b, 5, 100, b_ih_l0b, b_hh_l0b, 105, pk0b, 16, idx); break;
    case 2: pack_body(w_hh_l1f, 100, nullptr, 0, 0, b_ih_l1f, b_hh_l1f, -1, pkhh, 16, idx); break;
    case 3: pack_body(w_ih_l1f, 200, nullptr, 0, 0, b_ih_l1f, b_hh_l1f, 200, pkxg, 28, idx); break;
    default: pack_body(w_ih_l1b, 200, nullptr, 0, 0, b_ih_l1b, b_hh_l1b, 200, pk1b, 28, idx);
  }
}

// ------------- layer 0 scan (grid = 128 x 2 dirs, 1024 thr) -----------------
// R16 structure: 16 busy waves x 2 tiles (A=w, B=w+16), up/down lane split,
// partner8 swizzle spread; h-store tid<200, x-load tid<40 (overlap busy).
__global__ __launch_bounds__(1024, 1) void lstm_l0(
    const float* __restrict__ x,
    const unsigned short* __restrict__ pk_f, const unsigned short* __restrict__ pk_b,
    unsigned short* __restrict__ h0fT, unsigned short* __restrict__ h0bT) {
  __shared__ __align__(16) short A_s[2][16][16][8];  // [buf][kg][m16][jj], K=128

  const int tid = threadIdx.x;
  const int lane = tid & 63, w = tid >> 6;       // 16 waves
  const int q = lane >> 4, l16 = lane & 15;
  const int b0 = blockIdx.x * MB;
  const int dir = blockIdx.y;
  const unsigned short* pk = dir ? pk_b : pk_f;
  unsigned short* hT = dir ? h0bT : h0fT;

  for (int i = tid; i < 2 * 16 * 16 * 8; i += 1024) ((short*)A_s)[i] = 0;

  const int mtA = w, mtB = w + 16;
  const bool bvalid = (mtB < NT);
  bf16x8 wfA[4], wfB[4];
#pragma unroll
  for (int kt = 0; kt < 4; ++kt) {
    wfA[kt] = *(const bf16x8*)(pk + ((size_t)(kt * 4 + q) * NP + mtA * 16 + l16) * 8);
    wfB[kt] = *(const bf16x8*)(pk + ((size_t)(kt * 4 + q) * NP + mtB * 16 + l16) * 8);
  }
  float c = 0.f;
  const bool up = (l16 >= 8);
  const int mm = l16 & 7;
  const int j = (up ? mtB : mtA) * 4 + q;
  const bool valid = up ? bvalid : true;
  const int xm = tid / IN_, xe = tid - xm * IN_;              // x loader (tid<40)
  const int sm = tid / 25, sj = (tid - (tid / 25) * 25) * 4;  // h store (tid<200)
  const float* xp = x + ((size_t)(b0 + xm) * Tt + (dir ? Tt - 2 : 1)) * IN_ + xe;
  const int xstride = dir ? -IN_ : IN_;
  unsigned short* hp =
      hT + ((size_t)(dir ? Tt - 1 : 0) * Bsz + b0 + sm) * H + sj;
  const int hstride = dir ? -(Bsz * H) : (Bsz * H);
  __syncthreads();
  if (tid < 16) {  // bias-one col k=105 (kg13,jj1), both bufs
    A_s[0][13][tid][1] = (short)f2bf(1.f);
    A_s[1][13][tid][1] = (short)f2bf(1.f);
  }
  if (tid < MB * IN_) {  // x(t_first) -> buf0, direct f32 read
    int t0 = dir ? (Tt - 1) : 0;
    int k = 100 + xe;
    A_s[0][k >> 3][xm][k & 7] =
        (short)f2bf(x[((size_t)(b0 + xm) * Tt + t0) * IN_ + xe]);
  }
  __syncthreads();

  int p = 0;
  for (int step = 0; step < Tt; ++step) {
    if (step > 0 && tid < 200) {  // coalesced store of h(prev) from buf p
      uint2 hv = *(const uint2*)&A_s[p][sj >> 3][sm][sj & 7];
      *(uint2*)hp = hv;
      hp += hstride;
    }
    float xn = 0.f;
    const bool do_x = (tid < MB * IN_) && (step < Tt - 1);
    if (do_x) { xn = *xp; xp += xstride; }
    bf16x8 hfrag[4];
#pragma unroll
    for (int kt = 0; kt < 4; ++kt) hfrag[kt] = *(const bf16x8*)A_s[p][kt * 4 + q][l16];
    f32x4 accA = (f32x4){0.f, 0.f, 0.f, 0.f};
    f32x4 accB = (f32x4){0.f, 0.f, 0.f, 0.f};
#pragma unroll
    for (int kt = 0; kt < 4; ++kt)
      accA = __builtin_amdgcn_mfma_f32_16x16x32_bf16(wfA[kt], hfrag[kt], accA, 0, 0, 0);
    if (bvalid) {
#pragma unroll
      for (int kt = 0; kt < 4; ++kt)
        accB = __builtin_amdgcn_mfma_f32_16x16x32_bf16(wfB[kt], hfrag[kt], accB, 0, 0, 0);
    }
    float pb0 = partner8(accB[0]), pb1 = partner8(accB[1]);
    float pb2 = partner8(accB[2]), pb3 = partner8(accB[3]);
    float g0 = up ? pb0 : accA[0];
    float g1 = up ? pb1 : accA[1];
    float g2 = up ? pb2 : accA[2];
    float g3 = up ? pb3 : accA[3];
    float cc = sigm(g1) * c + sigm(g0) * tanhf_(g2);
    c = cc;
    float h = sigm(g3) * tanhf_(cc);
    if (valid) A_s[1 - p][j >> 3][mm][j & 7] = (short)f2bf(h);
    if (do_x) {
      int k = 100 + xe;
      A_s[1 - p][k >> 3][xm][k & 7] = (short)f2bf(xn);
    }
    __syncthreads();
    p ^= 1;
  }
  if (tid < 200) *(uint2*)hp = *(const uint2*)&A_s[p][sj >> 3][sm][sj & 7];  // final h
}

// ---- xgT[t*1024+b][400] = [h0f|h0b] @ W_ih_l1f^T + bias (fp16, interleaved) --
// 512 resident blocks x NGRP=4 row-groups, double-buffered LDS, async stage.
__global__ __launch_bounds__(1024, 1) void gemm_xg(
    const unsigned short* __restrict__ h0fT, const unsigned short* __restrict__ h0bT,
    const unsigned short* __restrict__ pkw, __half* __restrict__ xg) {
  __shared__ __align__(16) short B_s[2][28][64][8];  // K=224 aug (k=200 bias-one)
  const int tid = threadIdx.x;
  const int lane = tid & 63, w = tid >> 6;   // 16 waves
  const int q = lane >> 4, l16 = lane & 15;

  // static init: kg 25..27 both buffers (zero + bias-one at k=200, jj=0)
#pragma unroll
  for (int b = 0; b < 2; ++b)
    for (int i = tid; i < 3 * 64 * 8; i += 1024) {
      int jj = i & 7, gl = i >> 9;
      ((short*)&B_s[b][25][0][0])[i] = (short)((gl == 0 && jj == 0) ? f2bf(1.f) : 0);
    }

  const int mtA = w, mtB = w + 16;
  const bool bvalid = (mtB < NT);
  bf16x8 wfA[7], wfB[7];
#pragma unroll
  for (int kt = 0; kt < 7; ++kt) {
    wfA[kt] = *(const bf16x8*)(pkw + ((size_t)(kt * 4 + q) * NP + mtA * 16 + l16) * 8);
    wfB[kt] = *(const bf16x8*)(pkw + ((size_t)(kt * 4 + q) * NP + mtB * 16 + l16) * 8);
  }
  const int jA = mtA * 4 + q, jB = mtB * 4 + q;

  // staging tasks: idx -> (m=idx/25, j0=(idx%25)*4); tid owns idx=tid and
  // (tid<576) idx=tid+1024. 1600 tasks stage 64 rows x [h0f|h0b].
  const int t0m = tid / 25, t0j = (tid - t0m * 25) * 4;
  const int t1 = tid + 1024;
  const int t1m = t1 / 25, t1j = (t1 - t1m * 25) * 4;
  uint2 sf0, sb0, sf1, sb1;

#define XG_ISSUE(GRP)                                                  \
  {                                                                    \
    size_t base_ = (size_t)(GRP)*64 * H;                               \
    sf0 = *(const uint2*)(h0fT + base_ + t0m * H + t0j);               \
    sb0 = *(const uint2*)(h0bT + base_ + t0m * H + t0j);               \
    if (tid < 576) {                                                   \
      sf1 = *(const uint2*)(h0fT + base_ + t1m * H + t1j);             \
      sb1 = *(const uint2*)(h0bT + base_ + t1m * H + t1j);             \
    }                                                                  \
  }
#define XG_COMMIT(BUF)                                                 \
  {                                                                    \
    *(uint2*)&B_s[BUF][t0j >> 3][t0m][t0j & 7] = sf0;                  \
    int k0_ = 100 + t0j;                                               \
    *(uint2*)&B_s[BUF][k0_ >> 3][t0m][k0_ & 7] = sb0;                  \
    if (tid < 576) {                                                   \
      *(uint2*)&B_s[BUF][t1j >> 3][t1m][t1j & 7] = sf1;                \
      int k1_ = 100 + t1j;                                             \
      *(uint2*)&B_s[BUF][k1_ >> 3][t1m][k1_ & 7] = sb1;                \
    }                                                                  \
  }

  const int g0 = blockIdx.x;
  XG_ISSUE(g0);
  XG_COMMIT(0);
  __syncthreads();

  for (int i = 0; i < NGRP; ++i) {
    if (i < NGRP - 1) XG_ISSUE(g0 + GSTRIDE * (i + 1));  // issue early
    const short(*Bb)[64][8] = B_s[i & 1];
    const int r0 = (g0 + GSTRIDE * i) * 64;
#pragma unroll
    for (int rg = 0; rg < 4; ++rg) {
      f32x4 accA = (f32x4){0.f, 0.f, 0.f, 0.f};
      f32x4 accB = (f32x4){0.f, 0.f, 0.f, 0.f};
#pragma unroll
      for (int kt = 0; kt < 7; ++kt) {
        bf16x8 hf = *(const bf16x8*)Bb[kt * 4 + q][rg * 16 + l16];
        accA = __builtin_amdgcn_mfma_f32_16x16x32_bf16(wfA[kt], hf, accA, 0, 0, 0);
        if (bvalid)
          accB = __builtin_amdgcn_mfma_f32_16x16x32_bf16(wfB[kt], hf, accB, 0, 0, 0);
      }
      const size_t row = (size_t)(r0 + rg * 16 + l16);
      {
        __half2 h01 = __floats2half2_rn(accA[0], accA[1]);
        __half2 h23 = __floats2half2_rn(accA[2], accA[3]);
        uint2 st; *(__half2*)&st.x = h01; *(__half2*)&st.y = h23;
        *(uint2*)(xg + row * G + 4 * jA) = st;
      }
      if (bvalid) {
        __half2 h01 = __floats2half2_rn(accB[0], accB[1]);
        __half2 h23 = __floats2half2_rn(accB[2], accB[3]);
        uint2 st; *(__half2*)&st.x = h01; *(__half2*)&st.y = h23;
        *(uint2*)(xg + row * G + 4 * jB) = st;
      }
    }
    if (i < NGRP - 1) XG_COMMIT((i & 1) ^ 1);  // commit late, other buffer
    __syncthreads();
  }
#undef XG_ISSUE
#undef XG_COMMIT
}

// ---- layer 1: MB1=4, 256 blocks, dense 4 tiles/wave (waves 0..6 busy) ------
__global__ __launch_bounds__(1024, 1) void lstm_l1(
    const unsigned short* __restrict__ h0fT, const unsigned short* __restrict__ h0bT,
    const unsigned short* __restrict__ pk_hh, const unsigned short* __restrict__ pk1b,
    const __half* __restrict__ xg,
    const float* __restrict__ fc_w, const float* __restrict__ fc_b,
    float* __restrict__ out) {
  __shared__ __align__(16) short A_s[2][16][16][8];      // h1, K=128
  __shared__ __align__(16) short A2_s[28][16][8];        // epilogue [h0|1] K=224
  __shared__ float hf_s[MB1][H];
  __shared__ float hb_s[MB1][H];
  __shared__ float fcw_s[3 * D1];
  __shared__ float fcb_s[3];
  __shared__ float logit_s[MB1][3];

  const int tid = threadIdx.x;
  const int lane = tid & 63, w = tid >> 6;   // 16 waves
  const int q = lane >> 4, l16 = lane & 15;
  const int b0 = blockIdx.x * MB1;           // 256 blocks
  const uint2* xg2 = (const uint2*)xg;       // 100 uint2 per (t,b) row

  for (int i = tid; i < 2 * 16 * 16 * 8; i += 1024) ((short*)A_s)[i] = 0;
  for (int i = tid; i < 25 * 16 * 8; i += 1024) ((short*)A2_s)[i] = 0;  // kg 0..24
  for (int i = tid; i < 3 * 16 * 8; i += 1024) {  // A2 kg25..27 zero + bias-one
    int jj = i & 7, gl = i >> 7;
    ((short*)&A2_s[25][0][0])[i] = (short)((gl == 0 && jj == 0) ? f2bf(1.f) : 0);
  }
  for (int i = tid; i < 3 * D1; i += 1024) fcw_s[i] = fc_w[i];
  if (tid < 3) fcb_s[tid] = fc_b[tid];

  const bool busy = (w < 7);                 // waves 0..6 own tiles 4w..4w+3
  const int m = l16 & 3, g16 = l16 >> 2;
  const int myMt = w * 4 + g16;
  const int jme = myMt * 4 + q;              // my element's j (>=100 invalid)
  const bool evalid = busy && (myMt < NT);
  int mts[4]; bool tv[4];
  bf16x8 wf[4][4];
  if (busy) {
#pragma unroll
    for (int i = 0; i < 4; ++i) {
      int mt = w * 4 + i; mts[i] = mt; tv[i] = (mt < NT);
#pragma unroll
      for (int kt = 0; kt < 4; ++kt)
        wf[i][kt] = *(const bf16x8*)(pk_hh + ((size_t)(kt * 4 + q) * NP + mt * 16 + l16) * 8);
    }
  }
  float c = 0.f;
  // per-lane own-element xg, running pointer (+102400 uint2 per t);
  // invalid jme (<=111) reads <=96B past the row — lands in ws, unused.
  const uint2* xgp = xg2 + (size_t)(b0 + m) * 100 + jme;
  uint2 xgCur = {0, 0};
  if (busy) { xgCur = *xgp; xgp += Bsz * 100; }
  __syncthreads();

  int p = 0;
  for (int t = 0; t < Tt; ++t) {
    if (busy) {
      uint2 xgNxt = xgCur;
      if (t < Tt - 1) { xgNxt = *xgp; xgp += Bsz * 100; }
      bf16x8 hfrag[4];
      // [l16] read: cols 4..15 hold write-time duplicates of rows 0..3.
#pragma unroll
      for (int kt = 0; kt < 4; ++kt) hfrag[kt] = *(const bf16x8*)A_s[p][kt * 4 + q][l16];
      f32x4 acc[4];
#pragma unroll
      for (int i = 0; i < 4; ++i) {
        acc[i] = (f32x4){0.f, 0.f, 0.f, 0.f};
        if (!tv[i]) continue;
#pragma unroll
        for (int kt = 0; kt < 4; ++kt)
          acc[i] = __builtin_amdgcn_mfma_f32_16x16x32_bf16(wf[i][kt], hfrag[kt], acc[i], 0, 0, 0);
      }
      float2 x01 = __half22float2(*(const __half2*)&xgCur.x);
      float2 x23 = __half22float2(*(const __half2*)&xgCur.y);
      float xr[4] = {x01.x, x01.y, x23.x, x23.y};
      float gr[4];
#pragma unroll
      for (int r = 0; r < 4; ++r) {
        float lo = (g16 & 1) ? acc[1][r] : acc[0][r];
        float hi = (g16 & 1) ? acc[3][r] : acc[2][r];
        gr[r] = ((g16 & 2) ? hi : lo) + xr[r];
      }
      float cc = sigm(gr[1]) * c + sigm(gr[0]) * tanhf_(gr[2]);
      c = cc;
      float h = sigm(gr[3]) * tanhf_(cc);
      if (evalid) {  // write-dup into all 4 mirror columns
        short hh = (short)f2bf(h);
        A_s[1 - p][jme >> 3][m][jme & 7] = hh;
        A_s[1 - p][jme >> 3][m + 4][jme & 7] = hh;
        A_s[1 - p][jme >> 3][m + 8][jme & 7] = hh;
        A_s[1 - p][jme >> 3][m + 12][jme & 7] = hh;
        if (t == Tt - 1) hf_s[m][jme] = h;
      }
      xgCur = xgNxt;
    }
    __syncthreads();
    p ^= 1;
  }

  // ---- layer-1 backward single step at t=T-1 (h=c=0) ----
  {
    const size_t base = ((size_t)(Tt - 1) * Bsz + b0) * H;
    if (tid < 100) {  // stage rows m=0..3 only (this block's batch)
      int m2 = tid / 25, j0 = (tid - (tid / 25) * 25) * 4;
      *(uint2*)&A2_s[j0 >> 3][m2][j0 & 7] = *(const uint2*)(h0fT + base + m2 * H + j0);
      int k = 100 + j0;
      *(uint2*)&A2_s[k >> 3][m2][k & 7] = *(const uint2*)(h0bT + base + m2 * H + j0);
    }
  }
  __syncthreads();
  if (busy) {
    f32x4 acc[4];
#pragma unroll
    for (int i = 0; i < 4; ++i) acc[i] = (f32x4){0.f, 0.f, 0.f, 0.f};
#pragma unroll
    for (int kt = 0; kt < 7; ++kt) {
      bf16x8 hf = *(const bf16x8*)A2_s[kt * 4 + q][l16 & 3];  // one-shot dup-read
#pragma unroll
      for (int i = 0; i < 4; ++i) {
        if (!tv[i]) continue;
        bf16x8 wfb = *(const bf16x8*)(pk1b + ((size_t)(kt * 4 + q) * NP + mts[i] * 16 + l16) * 8);
        acc[i] = __builtin_amdgcn_mfma_f32_16x16x32_bf16(wfb, hf, acc[i], 0, 0, 0);
      }
    }
    float gr[4];
#pragma unroll
    for (int r = 0; r < 4; ++r) {
      float lo = (g16 & 1) ? acc[1][r] : acc[0][r];
      float hi = (g16 & 1) ? acc[3][r] : acc[2][r];
      gr[r] = (g16 & 2) ? hi : lo;
    }
    float cc = sigm(gr[0]) * tanhf_(gr[2]);   // c_prev = 0
    if (evalid) hb_s[m][jme] = sigm(gr[3]) * tanhf_(cc);
  }
  __syncthreads();

  // ---- FC (3x200) + softmax ----
  if (tid < MB1 * 3) {
    int mr = tid / 3, cls = tid - mr * 3;
    float s = fcb_s[cls];
    for (int jj = 0; jj < H; ++jj) s += fcw_s[cls * D1 + jj] * hf_s[mr][jj];
    for (int jj = 0; jj < H; ++jj) s += fcw_s[cls * D1 + H + jj] * hb_s[mr][jj];
    logit_s[mr][cls] = s;
  }
  __syncthreads();
  if (tid < MB1) {
    float a = logit_s[tid][0], b = logit_s[tid][1], cc = logit_s[tid][2];
    float mx = fmaxf(a, fmaxf(b, cc));
    float e0 = __expf(a - mx), e1 = __expf(b - mx), e2 = __expf(cc - mx);
    float inv = 1.f / (e0 + e1 + e2);
    out[(b0 + tid) * 3 + 0] = e0 * inv;
    out[(b0 + tid) * 3 + 1] = e1 * inv;
    out[(b0 + tid) * 3 + 2] = e2 * inv;
  }
}

extern "C" void kernel_launch(void* const* d_in, const int* in_sizes, int n_in,
                              void* d_out, int out_size, void* d_ws, size_t ws_size,
                              hipStream_t stream) {
  const float* x        = (const float*)d_in[0];
  const float* w_ih_l0f = (const float*)d_in[1];
  const float* w_hh_l0f = (const float*)d_in[2];
  const float* b_ih_l0f = (const float*)d_in[3];
  const float* b_hh_l0f = (const float*)d_in[4];
  const float* w_ih_l0b = (const float*)d_in[5];
  const float* w_hh_l0b = (const float*)d_in[6];
  const float* b_ih_l0b = (const float*)d_in[7];
  const float* b_hh_l0b = (const float*)d_in[8];
  const float* w_ih_l1f = (const float*)d_in[9];
  const float* w_hh_l1f = (const float*)d_in[10];
  const float* b_ih_l1f = (const float*)d_in[11];
  const float* b_hh_l1f = (const float*)d_in[12];
  const float* w_ih_l1b = (const float*)d_in[13];
  // d_in[14] = w_hh_l1b unused (reverse dir at t=T-1 has h=0)
  const float* b_ih_l1b = (const float*)d_in[15];
  const float* b_hh_l1b = (const float*)d_in[16];
  const float* fc_w     = (const float*)d_in[17];
  const float* fc_b     = (const float*)d_in[18];

  unsigned short* h0fT = (unsigned short*)d_ws;
  unsigned short* h0bT = h0fT + (size_t)Tt * Bsz * H;
  __half* xgT          = (__half*)(h0bT + (size_t)Tt * Bsz * H);
  unsigned short* pk0f = (unsigned short*)(xgT + (size_t)Tt * Bsz * G);
  unsigned short* pk0b = pk0f + 16 * NP * 8;
  unsigned short* pkhh = pk0b + 16 * NP * 8;
  unsigned short* pkxg = pkhh + 16 * NP * 8;
  unsigned short* pk1b = pkxg + 28 * NP * 8;

  pack_all<<<dim3(448, 5), 256, 0, stream>>>(
      w_hh_l0f, w_ih_l0f, b_ih_l0f, b_hh_l0f,
      w_hh_l0b, w_ih_l0b, b_ih_l0b, b_hh_l0b,
      w_hh_l1f, b_ih_l1f, b_hh_l1f,
      w_ih_l1f, w_ih_l1b, b_ih_l1b, b_hh_l1b,
      pk0f, pk0b, pkhh, pkxg, pk1b);

  lstm_l0<<<dim3(Bsz / MB, 2), 1024, 0, stream>>>(x, pk0f, pk0b, h0fT, h0bT);
  gemm_xg<<<GSTRIDE, 1024, 0, stream>>>(h0fT, h0bT, pkxg, xgT);
  lstm_l1<<<Bsz / MB1, 1024, 0, stream>>>(h0fT, h0bT, pkhh, pk1b, xgT,
                                          fc_w, fc_b, (float*)d_out);
}